// Round 6
// baseline (4028.913 us; speedup 1.0000x reference)
//
#include <hip/hip_runtime.h>
#include <math.h>

#define NG 8192          // graphs
#define NPG 32           // nodes per graph
#define NN (NG*NPG)      // 262144 nodes
#define NE (NN*4)        // 1048576 edges per side
#define EPG 128          // edges per graph
#define NEL (EPG+NPG)    // edges + self loops
#define FIN 70
#define DIM 128
#define XS 136           // x/h2 row stride in floats
#define WPS 18           // transposed W-panel row stride (floats)
#define NB 4
#define DK 64
#define NREL 86

typedef __attribute__((ext_vector_type(4))) float f32x4;

struct Smem {
  float x[NPG][XS];         // 17.4KB node features
  float h2[NPG][XS];        // 17.4KB x @ W (f32); RESCAL u[4][*]
  union {
    float wpt[DIM][WPS];    // 9.2KB transposed W k-panel: wpt[c][kk] = W[kp+kk][c]
    float P[2][NPG][NPG];   // 8KB attention matrix [head][src][dst]
  } u;
  int   srcl[EPG];
  int   dstl[EPG];
  float alpha[2][NEL];
  float asrc[NPG][2];
  float adst[NPG][2];
  float den[NPG][2];
  float mh[2];
  float wred[4][2];
  float pl[NPG];
  float ql[NPG];
  float sval[NPG];
  float sacc[NPG];
  float repr[2][NB][DIM];
  float keysl[NB][DK];
  float querl[NB][DK];
  float attw[NB*NB];
  float scl[2][NB];
  float red[NB*NB];
};

__global__ __launch_bounds__(256) void relnorm_kernel(
    const float* __restrict__ re, float* __restrict__ outn) {
  int r = blockIdx.x;
  const float* row = re + (size_t)r * (DIM*DIM);
  float s = 0.f;
  for (int i = threadIdx.x; i < DIM*DIM; i += 256) { float v = row[i]; s += v*v; }
  for (int w = 1; w < 64; w <<= 1) s += __shfl_xor(s, w);
  __shared__ float sred[4];
  if ((threadIdx.x & 63) == 0) sred[threadIdx.x >> 6] = s;
  __syncthreads();
  if (threadIdx.x == 0) outn[r] = sqrtf(sred[0]+sred[1]+sred[2]+sred[3]);
}

__global__ __launch_bounds__(256, 3) void ssi_kernel(
    const float* __restrict__ xh, const float* __restrict__ xt,
    const int* __restrict__ eh, const int* __restrict__ et,
    const int* __restrict__ rels,
    const float* __restrict__ W0, const float* __restrict__ Wr,
    const float* __restrict__ att_src, const float* __restrict__ att_dst,
    const float* __restrict__ gat_b,
    const float* __restrict__ srw, const float* __restrict__ srb,
    const float* __restrict__ sroot,
    const float* __restrict__ nw, const float* __restrict__ nb2,
    const float* __restrict__ inw, const float* __restrict__ inb,
    const float* __restrict__ wqm, const float* __restrict__ wkm,
    const float* __restrict__ cob, const float* __restrict__ coa,
    const float* __restrict__ rel_emb, const float* __restrict__ rnorm,
    float* __restrict__ out)
{
  __shared__ Smem sm;
  const int t = threadIdx.x;
  const int g = blockIdx.x;
  const int n0 = g * NPG;
  const int cL  = t & 31;        // column lane: owns cols cL + 32q, q=0..3
  const int nd0 = (t >> 5) * 4;  // 4 node rows

  for (int side = 0; side < 2; ++side) {
    const float* xin = side ? xt : xh;
    const int*   ed  = side ? et : eh;

    // ---- load edges (local ids) ----
    if (t < EPG) {
      sm.srcl[t] = ed[g*EPG + t] - n0;
      sm.dstl[t] = ed[NE + g*EPG + t] - n0;
    }
    // ---- input layernorm over FIN=70, zero-pad [70,80) ----
    {
      int n = t >> 3, j = t & 7;
      float s = 0.f, s2 = 0.f;
      for (int f = j; f < FIN; f += 8) {
        float v = xin[(size_t)(n0+n)*FIN + f];
        s += v; s2 += v*v;
      }
      for (int w = 1; w < 8; w <<= 1) { s += __shfl_xor(s, w); s2 += __shfl_xor(s2, w); }
      float mu  = s * (1.f/FIN);
      float var = s2 * (1.f/FIN) - mu*mu;
      float inv = rsqrtf(var + 1e-5f);
      for (int f = j; f < FIN; f += 8) {
        float v = xin[(size_t)(n0+n)*FIN + f];
        sm.x[n][f] = (v - mu) * inv * inw[f] + inb[f];
      }
      for (int f = FIN + j; f < 80; f += 8) sm.x[n][f] = 0.f;
    }
    __syncthreads();

    for (int li = 0; li < NB; ++li) {
      const float* W = (li == 0) ? W0 : (Wr + (size_t)(li-1)*DIM*DIM);
      const int K    = (li == 0) ? FIN : DIM;
      const int KP   = (li == 0) ? 80  : DIM;

      // ---- C1: h2 = x @ W (strided cols; transposed W panel; conflict-free) ----
      {
        float acc[4][4];
        #pragma unroll
        for (int m = 0; m < 4; ++m)
          #pragma unroll
          for (int q = 0; q < 4; ++q) acc[m][q] = 0.f;

        for (int kp = 0; kp < KP; kp += 16) {
          __syncthreads();   // protect wpt (and P-union) from previous readers
          for (int idx = t; idx < 16*DIM; idx += 256) {
            int kk = idx >> 7, c = idx & 127;
            int kg = kp + kk;
            sm.u.wpt[c][kk] = (kg < K) ? W[(size_t)kg*DIM + c] : 0.f;
          }
          __syncthreads();
          #pragma unroll
          for (int kk = 0; kk < 16; kk += 4) {
            float4 xa[4];
            #pragma unroll
            for (int m = 0; m < 4; ++m)
              xa[m] = *(const float4*)&sm.x[nd0+m][kp+kk];   // broadcast (2 addrs/wave)
            #pragma unroll
            for (int q = 0; q < 4; ++q) {
              const int cq = cL + 32*q;
              float2 w01 = *(const float2*)&sm.u.wpt[cq][kk];     // b64, 72B lane stride
              float2 w23 = *(const float2*)&sm.u.wpt[cq][kk+2];   // -> min-cycle (free)
              #pragma unroll
              for (int m = 0; m < 4; ++m) {
                acc[m][q] += xa[m].x*w01.x + xa[m].y*w01.y
                           + xa[m].z*w23.x + xa[m].w*w23.y;
              }
            }
          }
        }
        __syncthreads();   // wpt dead; C2 may now zero P (union)
        #pragma unroll
        for (int m = 0; m < 4; ++m)
          #pragma unroll
          for (int q = 0; q < 4; ++q)
            sm.h2[nd0+m][cL + 32*q] = acc[m][q];   // b32, 4B lane stride (free)
      }
      __syncthreads();

      // ---- C2: a_src/a_dst per (node, head); also zero P ----
      {
        int n = t >> 3, hd = (t >> 2) & 1, j = t & 3;
        const float* as = att_src + ((size_t)li*2 + hd)*64;
        const float* ad = att_dst + ((size_t)li*2 + hd)*64;
        float ss = 0.f, sd = 0.f;
        #pragma unroll
        for (int uu = 0; uu < 16; ++uu) {
          int cl = uu*4 + j;
          float hv = sm.h2[n][hd*64 + cl];
          ss += hv * as[cl];
          sd += hv * ad[cl];
        }
        ss += __shfl_xor(ss,1); ss += __shfl_xor(ss,2);
        sd += __shfl_xor(sd,1); sd += __shfl_xor(sd,2);
        if (j == 0) { sm.asrc[n][hd] = ss; sm.adst[n][hd] = sd; }
        float4* Pf = (float4*)&sm.u.P[0][0][0];
        float4 z4 = make_float4(0.f,0.f,0.f,0.f);
        Pf[t*2] = z4; Pf[t*2+1] = z4;
      }
      __syncthreads();

      // ---- C3: alpha = leaky_relu(a_src[s] + a_dst[d]) ----
      if (t < NEL) {
        int s = (t < EPG) ? sm.srcl[t] : (t - EPG);
        int d = (t < EPG) ? sm.dstl[t] : (t - EPG);
        #pragma unroll
        for (int hd = 0; hd < 2; ++hd) {
          float a = sm.asrc[s][hd] + sm.adst[d][hd];
          sm.alpha[hd][t] = (a > 0.f) ? a : 0.2f*a;
        }
      }
      __syncthreads();

      // ---- C4a: per-head block max (softmax shift; scale-invariant) ----
      {
        float a0 = (t < NEL) ? sm.alpha[0][t] : -1e30f;
        float a1 = (t < NEL) ? sm.alpha[1][t] : -1e30f;
        for (int w = 1; w < 64; w <<= 1) {
          a0 = fmaxf(a0, __shfl_xor(a0, w));
          a1 = fmaxf(a1, __shfl_xor(a1, w));
        }
        if ((t & 63) == 0) { sm.wred[t>>6][0] = a0; sm.wred[t>>6][1] = a1; }
      }
      __syncthreads();
      if (t < 2) {
        sm.mh[t] = fmaxf(fmaxf(sm.wred[0][t], sm.wred[1][t]),
                         fmaxf(sm.wred[2][t], sm.wred[3][t]));
      }
      __syncthreads();

      // ---- C4b: scatter exp into P[h][s][d] ----
      if (t < NEL) {
        int s = (t < EPG) ? sm.srcl[t] : (t - EPG);
        int d = (t < EPG) ? sm.dstl[t] : (t - EPG);
        float e0 = expf(sm.alpha[0][t] - sm.mh[0]);
        float e1 = expf(sm.alpha[1][t] - sm.mh[1]);
        atomicAdd(&sm.u.P[0][s][d], e0);
        atomicAdd(&sm.u.P[1][s][d], e1);
      }
      __syncthreads();

      // ---- C4c: den[d][h] = 1/(col-sum + eps) ----
      if (t < 64) {
        int d = t & 31, hd = t >> 5;
        float s = 0.f;
        for (int ss = 0; ss < NPG; ++ss) s += sm.u.P[hd][ss][d];
        sm.den[d][hd] = 1.f / (s + 1e-16f);
      }
      __syncthreads();

      // ---- C5: x = (P^T h2)*dinv + bias (strided cols; conflict-free) ----
      {
        float acc[4][4];
        #pragma unroll
        for (int m = 0; m < 4; ++m)
          #pragma unroll
          for (int q = 0; q < 4; ++q) acc[m][q] = 0.f;
        for (int s = 0; s < NPG; ++s) {
          f32x4 p0 = *(const f32x4*)&sm.u.P[0][s][nd0];   // broadcast
          f32x4 p1 = *(const f32x4*)&sm.u.P[1][s][nd0];   // broadcast
          float h0 = sm.h2[s][cL];        // b32, 4B lane stride (free)
          float h1 = sm.h2[s][cL+32];
          float hv2 = sm.h2[s][cL+64];
          float h3 = sm.h2[s][cL+96];
          #pragma unroll
          for (int m = 0; m < 4; ++m) {
            acc[m][0] += p0[m]*h0;
            acc[m][1] += p0[m]*h1;
            acc[m][2] += p1[m]*hv2;
            acc[m][3] += p1[m]*h3;
          }
        }
        float b0 = gat_b[(size_t)li*DIM + cL];
        float b1 = gat_b[(size_t)li*DIM + cL+32];
        float b2 = gat_b[(size_t)li*DIM + cL+64];
        float b3 = gat_b[(size_t)li*DIM + cL+96];
        #pragma unroll
        for (int m = 0; m < 4; ++m) {
          float d0 = sm.den[nd0+m][0];
          float d1 = sm.den[nd0+m][1];
          sm.x[nd0+m][cL]    = acc[m][0]*d0 + b0;
          sm.x[nd0+m][cL+32] = acc[m][1]*d0 + b1;
          sm.x[nd0+m][cL+64] = acc[m][2]*d1 + b2;
          sm.x[nd0+m][cL+96] = acc[m][3]*d1 + b3;
        }
      }
      __syncthreads();

      // ---- C6a: p = x.rw, q = x.root_w per node; zero sacc ----
      {
        int n = t >> 3, j = t & 7;
        const float* rw = srw   + (size_t)li*DIM;
        const float* ro = sroot + (size_t)li*DIM;
        float p = 0.f, q = 0.f;
        #pragma unroll
        for (int uu = 0; uu < 16; ++uu) {
          int c = uu*8 + j;
          float xv = sm.x[n][c];
          p += xv * rw[c];
          q += xv * ro[c];
        }
        for (int w = 1; w < 8; w <<= 1) { p += __shfl_xor(p,w); q += __shfl_xor(q,w); }
        if (j == 0) { sm.pl[n] = p; sm.ql[n] = q; }
        if (t < NPG) sm.sacc[t] = 0.f;
      }
      __syncthreads();

      // ---- C6b-1: scatter aggr scores ----
      if (t < EPG) atomicAdd(&sm.sacc[sm.dstl[t]], sm.pl[sm.srcl[t]]);
      __syncthreads();

      // ---- C6b-2: per-graph softmax over 32 nodes ----
      if (t < NPG) {
        float s = sm.sacc[t] + srb[li] + sm.ql[t];
        float m = s;
        for (int w = 1; w < 32; w <<= 1) m = fmaxf(m, __shfl_xor(m, w));
        float ex = expf(s - m);
        float dn = ex;
        for (int w = 1; w < 32; w <<= 1) dn += __shfl_xor(dn, w);
        sm.sval[t] = ex / (dn + 1e-16f);
      }
      __syncthreads();

      // ---- C6c: repr[c] = sum_n x[n][c]*sval[n] ----
      if (t < DIM) {
        float a = 0.f;
        for (int n = 0; n < NPG; ++n) a += sm.x[n][t] * sm.sval[n];
        sm.repr[side][li][t] = a;
      }
      __syncthreads();

      // ---- C7: x = elu(layernorm(x)) (skipped for last layer) ----
      if (li < NB-1) {
        int n = t >> 3, j = t & 7;
        float s = 0.f, s2 = 0.f;
        #pragma unroll
        for (int uu = 0; uu < 16; ++uu) {
          float v = sm.x[n][uu*8 + j];
          s += v; s2 += v*v;
        }
        for (int w = 1; w < 8; w <<= 1) { s += __shfl_xor(s,w); s2 += __shfl_xor(s2,w); }
        float mu  = s * (1.f/DIM);
        float var = s2 * (1.f/DIM) - mu*mu;
        float inv = rsqrtf(var + 1e-5f);
        const float* wv = nw  + (size_t)li*DIM;
        const float* bv = nb2 + (size_t)li*DIM;
        #pragma unroll
        for (int uu = 0; uu < 16; ++uu) {
          int c = uu*8 + j;
          float v = (sm.x[n][c] - mu) * inv * wv[c] + bv[c];
          sm.x[n][c] = (v > 0.f) ? v : expm1f(v);
        }
        __syncthreads();
      }
    }  // layer loop
  }  // side loop

  // ---- F1: keys = rh @ wk, queries = rt @ wq ----
  {
    int i2 = t >> 6, k = t & 63;
    float ak = 0.f, aq = 0.f;
    for (int d = 0; d < DIM; ++d) {
      ak += sm.repr[0][i2][d] * wkm[(size_t)d*DK + k];
      aq += sm.repr[1][i2][d] * wqm[(size_t)d*DK + k];
    }
    sm.keysl[i2][k] = ak;
    sm.querl[i2][k] = aq;
  }
  // ---- F2b: repr norms ----
  {
    int sd = t >> 7, i = (t >> 5) & 3, j2 = t & 31;
    float s = 0.f;
    #pragma unroll
    for (int uu = 0; uu < 4; ++uu) {
      float v = sm.repr[sd][i][j2*4+uu];
      s += v*v;
    }
    for (int w = 1; w < 32; w <<= 1) s += __shfl_xor(s, w);
    if (j2 == 0) sm.scl[sd][i] = 1.f / fmaxf(sqrtf(s), 1e-12f);
  }
  __syncthreads();

  // ---- F2: att[i][j] ----
  {
    int pair = t >> 4, kk = t & 15;
    int i = pair >> 2, j = pair & 3;
    float a = 0.f;
    #pragma unroll
    for (int uu = 0; uu < 4; ++uu) {
      int k = kk*4+uu;
      a += tanhf(sm.keysl[i][k] + sm.querl[j][k] + cob[k]) * coa[k];
    }
    for (int w = 1; w < 16; w <<= 1) a += __shfl_xor(a, w);
    if (kk == 0) sm.attw[pair] = a;
  }
  // ---- F3: u[i][:] = repr_h[i] @ r_raw (into h2 rows 0..3) ----
  int rel = rels[g];
  if (t < DIM) {
    const float* rr = rel_emb + (size_t)rel * (DIM*DIM);
    float a0=0.f, a1=0.f, a2=0.f, a3=0.f;
    for (int d = 0; d < DIM; ++d) {
      float rv = rr[(size_t)d*DIM + t];
      a0 += sm.repr[0][0][d] * rv;
      a1 += sm.repr[0][1][d] * rv;
      a2 += sm.repr[0][2][d] * rv;
      a3 += sm.repr[0][3][d] * rv;
    }
    sm.h2[0][t]=a0; sm.h2[1][t]=a1; sm.h2[2][t]=a2; sm.h2[3][t]=a3;
  }
  __syncthreads();

  // ---- F4: scores + weighted sum ----
  {
    float rninv = 1.f / fmaxf(rnorm[rel], 1e-12f);
    int pair = t >> 4, kk = t & 15;
    int i = pair >> 2, j = pair & 3;
    float a = 0.f;
    #pragma unroll
    for (int uu = 0; uu < 8; ++uu) {
      int e = kk*8+uu;
      a += sm.h2[i][e] * sm.repr[1][j][e];
    }
    for (int w = 1; w < 16; w <<= 1) a += __shfl_xor(a, w);
    if (kk == 0)
      sm.red[pair] = sm.attw[pair] * a * sm.scl[0][i] * sm.scl[1][j] * rninv;
  }
  __syncthreads();
  if (t == 0) {
    float s = 0.f;
    for (int p = 0; p < NB*NB; ++p) s += sm.red[p];
    out[g] = s;
  }
}

extern "C" void kernel_launch(void* const* d_in, const int* in_sizes, int n_in,
                              void* d_out, int out_size, void* d_ws, size_t ws_size,
                              hipStream_t stream) {
  const float* xh      = (const float*)d_in[0];
  const float* xt      = (const float*)d_in[1];
  const int*   eh      = (const int*)d_in[2];
  const int*   et      = (const int*)d_in[3];
  // d_in[4] = batch (structurally n>>5; unused)
  const int*   rels    = (const int*)d_in[5];
  const float* W0      = (const float*)d_in[6];
  const float* Wr      = (const float*)d_in[7];
  const float* att_src = (const float*)d_in[8];
  const float* att_dst = (const float*)d_in[9];
  const float* gat_b   = (const float*)d_in[10];
  const float* srw     = (const float*)d_in[11];
  const float* srb     = (const float*)d_in[12];
  const float* sroot   = (const float*)d_in[13];
  const float* nw      = (const float*)d_in[14];
  const float* nb2     = (const float*)d_in[15];
  const float* inw     = (const float*)d_in[16];
  const float* inb     = (const float*)d_in[17];
  const float* wqm     = (const float*)d_in[18];
  const float* wkm     = (const float*)d_in[19];
  const float* cob     = (const float*)d_in[20];
  const float* coa     = (const float*)d_in[21];
  const float* rel_emb = (const float*)d_in[22];
  float* out   = (float*)d_out;
  float* rnorm = (float*)d_ws;   // 86 floats

  relnorm_kernel<<<NREL, 256, 0, stream>>>(rel_emb, rnorm);
  ssi_kernel<<<NG, 256, 0, stream>>>(xh, xt, eh, et, rels, W0, Wr, att_src, att_dst,
      gat_b, srw, srb, sroot, nw, nb2, inw, inb, wqm, wkm, cob, coa, rel_emb,
      rnorm, out);
}

// Round 7
// 1616.990 us; speedup vs baseline: 2.4916x; 2.4916x over previous
//
#include <hip/hip_runtime.h>
#include <math.h>

#define NG 8192          // graphs
#define NPG 32           // nodes per graph
#define NN (NG*NPG)      // 262144 nodes
#define NE (NN*4)        // 1048576 edges per side
#define EPG 128          // edges per graph
#define NEL (EPG+NPG)    // edges + self loops
#define FIN 70
#define DIM 128
#define XS 132           // x/h2 row stride in floats (4 mod 32 banks; 16B-aligned rows)
#define NB 4
#define DK 64
#define NREL 86

typedef __attribute__((ext_vector_type(8))) short short8;
typedef __attribute__((ext_vector_type(4))) float f32x4;
typedef __attribute__((ext_vector_type(4))) unsigned int u32x4;

__device__ inline unsigned cvtpk(float a, float b) {
  unsigned r;
  asm("v_cvt_pk_bf16_f32 %0, %1, %2" : "=v"(r) : "v"(a), "v"(b));
  return r;   // lo16 = bf16(a), hi16 = bf16(b), RNE
}
__device__ inline float lo16f(unsigned u) { return __uint_as_float(u << 16); }
__device__ inline float hi16f(unsigned u) { return __uint_as_float(u & 0xffff0000u); }

// 8 f32 -> hi/lo bf16x8 fragments (2-term split, v = hi + lo + O(2^-17 |v|))
__device__ inline void split8(const f32x4& a, const f32x4& b, short8& hi, short8& lo) {
  u32x4 H, L;
  #pragma unroll
  for (int p = 0; p < 2; ++p) {
    float x0 = a[2*p], x1 = a[2*p+1];
    unsigned h = cvtpk(x0, x1);
    H[p] = h;
    L[p] = cvtpk(x0 - lo16f(h), x1 - hi16f(h));
  }
  #pragma unroll
  for (int p = 0; p < 2; ++p) {
    float x0 = b[2*p], x1 = b[2*p+1];
    unsigned h = cvtpk(x0, x1);
    H[2+p] = h;
    L[2+p] = cvtpk(x0 - lo16f(h), x1 - hi16f(h));
  }
  hi = __builtin_bit_cast(short8, H);
  lo = __builtin_bit_cast(short8, L);
}

struct Smem {
  float x[NPG][XS];         // 16.9KB node features (f32)
  float h2[NPG][XS];        // 16.9KB x @ W (f32); RESCAL u[4][*]
  union {
    struct {                // GAT phases (C2..C5)
      float P[2][NPG][NPG]; // 8KB attention matrix [head][src][dst]
      float alpha[2][NEL];  // 1.25KB
    } a;
    struct {                // final phases (F1..F4)
      float keysl[NB][DK];
      float querl[NB][DK];
      float attw[NB*NB];
      float red[NB*NB];
    } f;
  } uu;
  int   srcl[EPG];
  int   dstl[EPG];
  float asrc[NPG][2];
  float adst[NPG][2];
  float den[NPG][2];
  float mh[2];
  float wred[4][2];
  float pl[NPG];
  float ql[NPG];
  float sval[NPG];
  float sacc[NPG];
  float repr[2][NB][DIM];   // 4KB readouts [side][layer][D]
  float scl[2][NB];
};

__global__ __launch_bounds__(256) void relnorm_kernel(
    const float* __restrict__ re, float* __restrict__ outn) {
  int r = blockIdx.x;
  const float* row = re + (size_t)r * (DIM*DIM);
  float s = 0.f;
  for (int i = threadIdx.x; i < DIM*DIM; i += 256) { float v = row[i]; s += v*v; }
  for (int w = 1; w < 64; w <<= 1) s += __shfl_xor(s, w);
  __shared__ float sred[4];
  if ((threadIdx.x & 63) == 0) sred[threadIdx.x >> 6] = s;
  __syncthreads();
  if (threadIdx.x == 0) outn[r] = sqrtf(sred[0]+sred[1]+sred[2]+sred[3]);
}

__global__ __launch_bounds__(256, 3) void ssi_kernel(
    const float* __restrict__ xh, const float* __restrict__ xt,
    const int* __restrict__ eh, const int* __restrict__ et,
    const int* __restrict__ rels,
    const float* __restrict__ W0, const float* __restrict__ Wr,
    const float* __restrict__ att_src, const float* __restrict__ att_dst,
    const float* __restrict__ gat_b,
    const float* __restrict__ srw, const float* __restrict__ srb,
    const float* __restrict__ sroot,
    const float* __restrict__ nw, const float* __restrict__ nb2,
    const float* __restrict__ inw, const float* __restrict__ inb,
    const float* __restrict__ wqm, const float* __restrict__ wkm,
    const float* __restrict__ cob, const float* __restrict__ coa,
    const float* __restrict__ rel_emb, const float* __restrict__ rnorm,
    float* __restrict__ out)
{
  __shared__ Smem sm;
  const int t = threadIdx.x;
  const int g = blockIdx.x;
  const int n0 = g * NPG;
  const int cL  = t & 31;        // C5 mapping: lane owns cols cL + 32q
  const int nd0 = (t >> 5) * 4;

  for (int side = 0; side < 2; ++side) {
    const float* xin = side ? xt : xh;
    const int*   ed  = side ? et : eh;

    // ---- load edges (local ids) ----
    if (t < EPG) {
      sm.srcl[t] = ed[g*EPG + t] - n0;
      sm.dstl[t] = ed[NE + g*EPG + t] - n0;
    }
    // ---- input layernorm over FIN=70, zero-pad [70,96) for MFMA k-coverage ----
    {
      int n = t >> 3, j = t & 7;
      float s = 0.f, s2 = 0.f;
      for (int f = j; f < FIN; f += 8) {
        float v = xin[(size_t)(n0+n)*FIN + f];
        s += v; s2 += v*v;
      }
      for (int w = 1; w < 8; w <<= 1) { s += __shfl_xor(s, w); s2 += __shfl_xor(s2, w); }
      float mu  = s * (1.f/FIN);
      float var = s2 * (1.f/FIN) - mu*mu;
      float inv = rsqrtf(var + 1e-5f);
      for (int f = j; f < FIN; f += 8) {
        float v = xin[(size_t)(n0+n)*FIN + f];
        sm.x[n][f] = (v - mu) * inv * inw[f] + inb[f];
      }
      for (int f = FIN + j; f < 96; f += 8) sm.x[n][f] = 0.f;
    }
    __syncthreads();

    for (int li = 0; li < NB; ++li) {
      // ---- C1: h2 = x @ W via MFMA, in-register 2-term bf16 split ----
      // A from LDS f32 x; B gathered from global W (L2-hot). No staging, no ws.
      {
        const int lw = t & 63;
        const int r0 = lw & 15;        // row (A) / col (B) within 16-tile
        const int g4 = lw >> 4;        // k-group
        const int nb = (t >> 6) * 32;  // wave's 32-col band
        const float* W = (li == 0) ? W0 : (Wr + (size_t)(li-1)*DIM*DIM);
        const int K  = (li == 0) ? FIN : DIM;
        const int KS = (li == 0) ? 3 : 4;
        f32x4 acc[2][2];
        #pragma unroll
        for (int mt = 0; mt < 2; ++mt)
          #pragma unroll
          for (int nt = 0; nt < 2; ++nt)
            acc[mt][nt] = (f32x4){0.f,0.f,0.f,0.f};
        for (int ks = 0; ks < KS; ++ks) {
          const int k0 = ks*32 + g4*8;
          short8 ah[2], al[2], bh[2], bl[2];
          #pragma unroll
          for (int mt = 0; mt < 2; ++mt) {
            f32x4 va = *(const f32x4*)&sm.x[mt*16 + r0][k0];
            f32x4 vb = *(const f32x4*)&sm.x[mt*16 + r0][k0+4];
            split8(va, vb, ah[mt], al[mt]);
          }
          #pragma unroll
          for (int nt = 0; nt < 2; ++nt) {
            const int c = nb + nt*16 + r0;
            f32x4 wa, wb;
            #pragma unroll
            for (int j = 0; j < 4; ++j) {
              int ka = k0 + j, kb = k0 + 4 + j;
              wa[j] = (ka < K) ? W[(size_t)ka*DIM + c] : 0.f;
              wb[j] = (kb < K) ? W[(size_t)kb*DIM + c] : 0.f;
            }
            split8(wa, wb, bh[nt], bl[nt]);
          }
          #pragma unroll
          for (int mt = 0; mt < 2; ++mt)
            #pragma unroll
            for (int nt = 0; nt < 2; ++nt) {
              acc[mt][nt] = __builtin_amdgcn_mfma_f32_16x16x32_bf16(ah[mt], bh[nt], acc[mt][nt], 0,0,0);
              acc[mt][nt] = __builtin_amdgcn_mfma_f32_16x16x32_bf16(ah[mt], bl[nt], acc[mt][nt], 0,0,0);
              acc[mt][nt] = __builtin_amdgcn_mfma_f32_16x16x32_bf16(al[mt], bh[nt], acc[mt][nt], 0,0,0);
              acc[mt][nt] = __builtin_amdgcn_mfma_f32_16x16x32_bf16(al[mt], bl[nt], acc[mt][nt], 0,0,0);
            }
        }
        // C/D: col = lane&15, row = (lane>>4)*4 + reg  [verified by R5 hi-path]
        #pragma unroll
        for (int mt = 0; mt < 2; ++mt)
          #pragma unroll
          for (int nt = 0; nt < 2; ++nt)
            #pragma unroll
            for (int q = 0; q < 4; ++q)
              sm.h2[mt*16 + g4*4 + q][nb + nt*16 + r0] = acc[mt][nt][q];
      }
      __syncthreads();

      // ---- C2: a_src/a_dst per (node, head); also zero P ----
      {
        int n = t >> 3, hd = (t >> 2) & 1, j = t & 3;
        const float* as = att_src + ((size_t)li*2 + hd)*64;
        const float* ad = att_dst + ((size_t)li*2 + hd)*64;
        float ss = 0.f, sd = 0.f;
        #pragma unroll
        for (int uu2 = 0; uu2 < 16; ++uu2) {
          int cl = uu2*4 + j;
          float hv = sm.h2[n][hd*64 + cl];
          ss += hv * as[cl];
          sd += hv * ad[cl];
        }
        ss += __shfl_xor(ss,1); ss += __shfl_xor(ss,2);
        sd += __shfl_xor(sd,1); sd += __shfl_xor(sd,2);
        if (j == 0) { sm.asrc[n][hd] = ss; sm.adst[n][hd] = sd; }
        float4* Pf = (float4*)&sm.uu.a.P[0][0][0];
        float4 z4 = make_float4(0.f,0.f,0.f,0.f);
        Pf[t*2] = z4; Pf[t*2+1] = z4;
      }
      __syncthreads();

      // ---- C3: alpha = leaky_relu(a_src[s] + a_dst[d]) ----
      if (t < NEL) {
        int s = (t < EPG) ? sm.srcl[t] : (t - EPG);
        int d = (t < EPG) ? sm.dstl[t] : (t - EPG);
        #pragma unroll
        for (int hd = 0; hd < 2; ++hd) {
          float a = sm.asrc[s][hd] + sm.adst[d][hd];
          sm.uu.a.alpha[hd][t] = (a > 0.f) ? a : 0.2f*a;
        }
      }
      __syncthreads();

      // ---- C4a: per-head block max (softmax shift; scale-invariant) ----
      {
        float a0 = (t < NEL) ? sm.uu.a.alpha[0][t] : -1e30f;
        float a1 = (t < NEL) ? sm.uu.a.alpha[1][t] : -1e30f;
        for (int w = 1; w < 64; w <<= 1) {
          a0 = fmaxf(a0, __shfl_xor(a0, w));
          a1 = fmaxf(a1, __shfl_xor(a1, w));
        }
        if ((t & 63) == 0) { sm.wred[t>>6][0] = a0; sm.wred[t>>6][1] = a1; }
      }
      __syncthreads();
      if (t < 2) {
        sm.mh[t] = fmaxf(fmaxf(sm.wred[0][t], sm.wred[1][t]),
                         fmaxf(sm.wred[2][t], sm.wred[3][t]));
      }
      __syncthreads();

      // ---- C4b: scatter exp into P[h][s][d] ----
      if (t < NEL) {
        int s = (t < EPG) ? sm.srcl[t] : (t - EPG);
        int d = (t < EPG) ? sm.dstl[t] : (t - EPG);
        float e0 = expf(sm.uu.a.alpha[0][t] - sm.mh[0]);
        float e1 = expf(sm.uu.a.alpha[1][t] - sm.mh[1]);
        atomicAdd(&sm.uu.a.P[0][s][d], e0);
        atomicAdd(&sm.uu.a.P[1][s][d], e1);
      }
      __syncthreads();

      // ---- C4c: den[d][h] = 1/(col-sum + eps) ----
      if (t < 64) {
        int d = t & 31, hd = t >> 5;
        float s = 0.f;
        for (int ss = 0; ss < NPG; ++ss) s += sm.uu.a.P[hd][ss][d];
        sm.den[d][hd] = 1.f / (s + 1e-16f);
      }
      __syncthreads();

      // ---- C5: x = (P^T h2)*dinv + bias (strided cols; conflict-free) ----
      {
        float acc[4][4];
        #pragma unroll
        for (int m = 0; m < 4; ++m)
          #pragma unroll
          for (int q = 0; q < 4; ++q) acc[m][q] = 0.f;
        for (int s = 0; s < NPG; ++s) {
          f32x4 p0 = *(const f32x4*)&sm.uu.a.P[0][s][nd0];   // broadcast
          f32x4 p1 = *(const f32x4*)&sm.uu.a.P[1][s][nd0];   // broadcast
          float h0 = sm.h2[s][cL];
          float h1 = sm.h2[s][cL+32];
          float hv2 = sm.h2[s][cL+64];
          float h3 = sm.h2[s][cL+96];
          #pragma unroll
          for (int m = 0; m < 4; ++m) {
            acc[m][0] += p0[m]*h0;
            acc[m][1] += p0[m]*h1;
            acc[m][2] += p1[m]*hv2;
            acc[m][3] += p1[m]*h3;
          }
        }
        float b0 = gat_b[(size_t)li*DIM + cL];
        float b1 = gat_b[(size_t)li*DIM + cL+32];
        float b2 = gat_b[(size_t)li*DIM + cL+64];
        float b3 = gat_b[(size_t)li*DIM + cL+96];
        #pragma unroll
        for (int m = 0; m < 4; ++m) {
          float d0 = sm.den[nd0+m][0];
          float d1 = sm.den[nd0+m][1];
          sm.x[nd0+m][cL]    = acc[m][0]*d0 + b0;
          sm.x[nd0+m][cL+32] = acc[m][1]*d0 + b1;
          sm.x[nd0+m][cL+64] = acc[m][2]*d1 + b2;
          sm.x[nd0+m][cL+96] = acc[m][3]*d1 + b3;
        }
      }
      __syncthreads();

      // ---- C6a: p = x.rw, q = x.root_w per node; zero sacc ----
      {
        int n = t >> 3, j = t & 7;
        const float* rw = srw   + (size_t)li*DIM;
        const float* ro = sroot + (size_t)li*DIM;
        float p = 0.f, q = 0.f;
        #pragma unroll
        for (int uu2 = 0; uu2 < 16; ++uu2) {
          int c = uu2*8 + j;
          float xv = sm.x[n][c];
          p += xv * rw[c];
          q += xv * ro[c];
        }
        for (int w = 1; w < 8; w <<= 1) { p += __shfl_xor(p,w); q += __shfl_xor(q,w); }
        if (j == 0) { sm.pl[n] = p; sm.ql[n] = q; }
        if (t < NPG) sm.sacc[t] = 0.f;
      }
      __syncthreads();

      // ---- C6b-1: scatter aggr scores ----
      if (t < EPG) atomicAdd(&sm.sacc[sm.dstl[t]], sm.pl[sm.srcl[t]]);
      __syncthreads();

      // ---- C6b-2: per-graph softmax over 32 nodes ----
      if (t < NPG) {
        float s = sm.sacc[t] + srb[li] + sm.ql[t];
        float m = s;
        for (int w = 1; w < 32; w <<= 1) m = fmaxf(m, __shfl_xor(m, w));
        float ex = expf(s - m);
        float dn = ex;
        for (int w = 1; w < 32; w <<= 1) dn += __shfl_xor(dn, w);
        sm.sval[t] = ex / (dn + 1e-16f);
      }
      __syncthreads();

      // ---- C6c: repr[c] = sum_n x[n][c]*sval[n] ----
      if (t < DIM) {
        float a = 0.f;
        for (int n = 0; n < NPG; ++n) a += sm.x[n][t] * sm.sval[n];
        sm.repr[side][li][t] = a;
      }
      __syncthreads();

      // ---- C7: x = elu(layernorm(x)) (skipped for last layer) ----
      if (li < NB-1) {
        int n = t >> 3, j = t & 7;
        float s = 0.f, s2 = 0.f;
        #pragma unroll
        for (int uu2 = 0; uu2 < 16; ++uu2) {
          float v = sm.x[n][uu2*8 + j];
          s += v; s2 += v*v;
        }
        for (int w = 1; w < 8; w <<= 1) { s += __shfl_xor(s,w); s2 += __shfl_xor(s2,w); }
        float mu  = s * (1.f/DIM);
        float var = s2 * (1.f/DIM) - mu*mu;
        float inv = rsqrtf(var + 1e-5f);
        const float* wv = nw  + (size_t)li*DIM;
        const float* bv = nb2 + (size_t)li*DIM;
        #pragma unroll
        for (int uu2 = 0; uu2 < 16; ++uu2) {
          int c = uu2*8 + j;
          float v = (sm.x[n][c] - mu) * inv * wv[c] + bv[c];
          sm.x[n][c] = (v > 0.f) ? v : expm1f(v);
        }
        __syncthreads();
      }
    }  // layer loop
  }  // side loop

  // ---- F1: keys = rh @ wk, queries = rt @ wq ----
  {
    int i2 = t >> 6, k = t & 63;
    float ak = 0.f, aq = 0.f;
    for (int d = 0; d < DIM; ++d) {
      ak += sm.repr[0][i2][d] * wkm[(size_t)d*DK + k];
      aq += sm.repr[1][i2][d] * wqm[(size_t)d*DK + k];
    }
    sm.uu.f.keysl[i2][k] = ak;
    sm.uu.f.querl[i2][k] = aq;
  }
  // ---- F2b: repr norms ----
  {
    int sd = t >> 7, i = (t >> 5) & 3, j2 = t & 31;
    float s = 0.f;
    #pragma unroll
    for (int uu2 = 0; uu2 < 4; ++uu2) {
      float v = sm.repr[sd][i][j2*4+uu2];
      s += v*v;
    }
    for (int w = 1; w < 32; w <<= 1) s += __shfl_xor(s, w);
    if (j2 == 0) sm.scl[sd][i] = 1.f / fmaxf(sqrtf(s), 1e-12f);
  }
  __syncthreads();

  // ---- F2: att[i][j] ----
  {
    int pair = t >> 4, kk = t & 15;
    int i = pair >> 2, j = pair & 3;
    float a = 0.f;
    #pragma unroll
    for (int uu2 = 0; uu2 < 4; ++uu2) {
      int k = kk*4+uu2;
      a += tanhf(sm.uu.f.keysl[i][k] + sm.uu.f.querl[j][k] + cob[k]) * coa[k];
    }
    for (int w = 1; w < 16; w <<= 1) a += __shfl_xor(a, w);
    if (kk == 0) sm.uu.f.attw[pair] = a;
  }
  // ---- F3: u[i][:] = repr_h[i] @ r_raw (into h2 rows 0..3) ----
  int rel = rels[g];
  if (t < DIM) {
    const float* rr = rel_emb + (size_t)rel * (DIM*DIM);
    float a0=0.f, a1=0.f, a2=0.f, a3=0.f;
    for (int d = 0; d < DIM; ++d) {
      float rv = rr[(size_t)d*DIM + t];
      a0 += sm.repr[0][0][d] * rv;
      a1 += sm.repr[0][1][d] * rv;
      a2 += sm.repr[0][2][d] * rv;
      a3 += sm.repr[0][3][d] * rv;
    }
    sm.h2[0][t]=a0; sm.h2[1][t]=a1; sm.h2[2][t]=a2; sm.h2[3][t]=a3;
  }
  __syncthreads();

  // ---- F4: scores + weighted sum ----
  {
    float rninv = 1.f / fmaxf(rnorm[rel], 1e-12f);
    int pair = t >> 4, kk = t & 15;
    int i = pair >> 2, j = pair & 3;
    float a = 0.f;
    #pragma unroll
    for (int uu2 = 0; uu2 < 8; ++uu2) {
      int e = kk*8+uu2;
      a += sm.h2[i][e] * sm.repr[1][j][e];
    }
    for (int w = 1; w < 16; w <<= 1) a += __shfl_xor(a, w);
    if (kk == 0)
      sm.uu.f.red[pair] = sm.uu.f.attw[pair] * a * sm.scl[0][i] * sm.scl[1][j] * rninv;
  }
  __syncthreads();
  if (t == 0) {
    float s = 0.f;
    for (int p = 0; p < NB*NB; ++p) s += sm.uu.f.red[p];
    out[g] = s;
  }
}

extern "C" void kernel_launch(void* const* d_in, const int* in_sizes, int n_in,
                              void* d_out, int out_size, void* d_ws, size_t ws_size,
                              hipStream_t stream) {
  const float* xh      = (const float*)d_in[0];
  const float* xt      = (const float*)d_in[1];
  const int*   eh      = (const int*)d_in[2];
  const int*   et      = (const int*)d_in[3];
  // d_in[4] = batch (structurally n>>5; unused)
  const int*   rels    = (const int*)d_in[5];
  const float* W0      = (const float*)d_in[6];
  const float* Wr      = (const float*)d_in[7];
  const float* att_src = (const float*)d_in[8];
  const float* att_dst = (const float*)d_in[9];
  const float* gat_b   = (const float*)d_in[10];
  const float* srw     = (const float*)d_in[11];
  const float* srb     = (const float*)d_in[12];
  const float* sroot   = (const float*)d_in[13];
  const float* nw      = (const float*)d_in[14];
  const float* nb2     = (const float*)d_in[15];
  const float* inw     = (const float*)d_in[16];
  const float* inb     = (const float*)d_in[17];
  const float* wqm     = (const float*)d_in[18];
  const float* wkm     = (const float*)d_in[19];
  const float* cob     = (const float*)d_in[20];
  const float* coa     = (const float*)d_in[21];
  const float* rel_emb = (const float*)d_in[22];
  float* out   = (float*)d_out;
  float* rnorm = (float*)d_ws;   // 86 floats (proven-good ws usage)

  relnorm_kernel<<<NREL, 256, 0, stream>>>(rel_emb, rnorm);
  ssi_kernel<<<NG, 256, 0, stream>>>(xh, xt, eh, et, rels, W0, Wr, att_src, att_dst,
      gat_b, srw, srb, sroot, nw, nb2, inw, inb, wqm, wkm, cob, coa, rel_emb,
      rnorm, out);
}

// Round 8
// 1432.798 us; speedup vs baseline: 2.8119x; 1.1286x over previous
//
#include <hip/hip_runtime.h>
#include <math.h>

#define NG 8192          // graphs
#define NPG 32           // nodes per graph
#define NN (NG*NPG)      // 262144 nodes
#define NE (NN*4)        // 1048576 edges per side
#define EPG 128          // edges per graph
#define NEL (EPG+NPG)    // edges + self loops
#define FIN 70
#define DIM 128
#define XS 132           // x row stride in floats
#define TS 36            // h2t / Pt row stride (u16 / f32 units): b64-aligned, 18-bank stride
#define NB 4
#define DK 64
#define NREL 86

typedef __attribute__((ext_vector_type(8))) short short8;
typedef __attribute__((ext_vector_type(4))) float f32x4;
typedef __attribute__((ext_vector_type(4))) unsigned int u32x4;

__device__ inline unsigned cvtpk(float a, float b) {
  unsigned r;
  asm("v_cvt_pk_bf16_f32 %0, %1, %2" : "=v"(r) : "v"(a), "v"(b));
  return r;   // lo16 = bf16(a), hi16 = bf16(b), RNE
}
__device__ inline float lo16f(unsigned u) { return __uint_as_float(u << 16); }
__device__ inline float hi16f(unsigned u) { return __uint_as_float(u & 0xffff0000u); }
__device__ inline float bf16f(unsigned short h) {
  return __uint_as_float(((unsigned int)h) << 16);
}

// 8 f32 -> hi/lo bf16x8 fragments (2-term split, v = hi + lo + O(2^-17 |v|))
__device__ inline void split8(const f32x4& a, const f32x4& b, short8& hi, short8& lo) {
  u32x4 H, L;
  #pragma unroll
  for (int p = 0; p < 2; ++p) {
    float x0 = a[2*p], x1 = a[2*p+1];
    unsigned h = cvtpk(x0, x1);
    H[p] = h;
    L[p] = cvtpk(x0 - lo16f(h), x1 - hi16f(h));
  }
  #pragma unroll
  for (int p = 0; p < 2; ++p) {
    float x0 = b[2*p], x1 = b[2*p+1];
    unsigned h = cvtpk(x0, x1);
    H[2+p] = h;
    L[2+p] = cvtpk(x0 - lo16f(h), x1 - hi16f(h));
  }
  hi = __builtin_bit_cast(short8, H);
  lo = __builtin_bit_cast(short8, L);
}

// 8 contiguous bf16 (8B-aligned) -> short8 via 2x b64
__device__ inline short8 ld8(const unsigned short* p) {
  union { short8 s; uint2 u[2]; } U;
  U.u[0] = *(const uint2*)p;
  U.u[1] = *(const uint2*)(p + 4);
  return U.s;
}

struct Smem {
  float x[NPG][XS];               // 16.9KB node features (f32)
  unsigned short h2thi[DIM][TS];  // 9.2KB h2 transposed, bf16 hi: h2thi[c][node]
  unsigned short h2tlo[DIM][TS];  // 9.2KB residual
  union {
    struct {                      // GAT phases
      float Pt[2][NPG][TS];       // 9.2KB P'[hd][dst][src]; after C4d reused as bf16 hi|lo
      float alpha[2][NEL];        // 1.28KB
    } a;
    struct {                      // final phases
      float keysl[NB][DK];
      float querl[NB][DK];
      float attw[NB*NB];
      float red[NB*NB];
      float u4[4][DIM];           // RESCAL u = repr_h @ r
    } f;
  } uu;
  int   srcl[EPG];
  int   dstl[EPG];
  float asrc[NPG][2];
  float adst[NPG][2];
  float den[NPG][2];
  float mh[2];
  float wred[4][2];
  float pl[NPG];
  float ql[NPG];
  float sval[NPG];
  float sacc[NPG];
  float repr[2][NB][DIM];
  float scl[2][NB];
};

__global__ __launch_bounds__(256) void relnorm_kernel(
    const float* __restrict__ re, float* __restrict__ outn) {
  int r = blockIdx.x;
  const float* row = re + (size_t)r * (DIM*DIM);
  float s = 0.f;
  for (int i = threadIdx.x; i < DIM*DIM; i += 256) { float v = row[i]; s += v*v; }
  for (int w = 1; w < 64; w <<= 1) s += __shfl_xor(s, w);
  __shared__ float sred[4];
  if ((threadIdx.x & 63) == 0) sred[threadIdx.x >> 6] = s;
  __syncthreads();
  if (threadIdx.x == 0) outn[r] = sqrtf(sred[0]+sred[1]+sred[2]+sred[3]);
}

__global__ __launch_bounds__(256, 3) void ssi_kernel(
    const float* __restrict__ xh, const float* __restrict__ xt,
    const int* __restrict__ eh, const int* __restrict__ et,
    const int* __restrict__ rels,
    const float* __restrict__ W0, const float* __restrict__ Wr,
    const float* __restrict__ att_src, const float* __restrict__ att_dst,
    const float* __restrict__ gat_b,
    const float* __restrict__ srw, const float* __restrict__ srb,
    const float* __restrict__ sroot,
    const float* __restrict__ nw, const float* __restrict__ nb2,
    const float* __restrict__ inw, const float* __restrict__ inb,
    const float* __restrict__ wqm, const float* __restrict__ wkm,
    const float* __restrict__ cob, const float* __restrict__ coa,
    const float* __restrict__ rel_emb, const float* __restrict__ rnorm,
    float* __restrict__ out)
{
  __shared__ Smem sm;
  const int t = threadIdx.x;
  const int g = blockIdx.x;
  const int n0 = g * NPG;
  const int lw = t & 63;
  const int r0 = lw & 15;        // MFMA row/col lane within 16-tile
  const int g4 = lw >> 4;        // MFMA k-group
  const int nb = (t >> 6) * 32;  // wave's 32-col band
  const int hdw = t >> 7;        // wave's head (cols 0..63 -> 0, 64..127 -> 1)

  for (int side = 0; side < 2; ++side) {
    const float* xin = side ? xt : xh;
    const int*   ed  = side ? et : eh;

    // ---- load edges (local ids) ----
    if (t < EPG) {
      sm.srcl[t] = ed[g*EPG + t] - n0;
      sm.dstl[t] = ed[NE + g*EPG + t] - n0;
    }
    // ---- input layernorm over FIN=70, zero-pad [70,96) for MFMA k-coverage ----
    {
      int n = t >> 3, j = t & 7;
      float s = 0.f, s2 = 0.f;
      for (int f = j; f < FIN; f += 8) {
        float v = xin[(size_t)(n0+n)*FIN + f];
        s += v; s2 += v*v;
      }
      for (int w = 1; w < 8; w <<= 1) { s += __shfl_xor(s, w); s2 += __shfl_xor(s2, w); }
      float mu  = s * (1.f/FIN);
      float var = s2 * (1.f/FIN) - mu*mu;
      float inv = rsqrtf(var + 1e-5f);
      for (int f = j; f < FIN; f += 8) {
        float v = xin[(size_t)(n0+n)*FIN + f];
        sm.x[n][f] = (v - mu) * inv * inw[f] + inb[f];
      }
      for (int f = FIN + j; f < 96; f += 8) sm.x[n][f] = 0.f;
    }
    __syncthreads();

    for (int li = 0; li < NB; ++li) {
      // ---- C1: h2 = x @ W via MFMA (in-register 2-term bf16 split);
      //      epilogue stores h2 TRANSPOSED bf16 hi/lo for C2/C5 ----
      {
        const float* W = (li == 0) ? W0 : (Wr + (size_t)(li-1)*DIM*DIM);
        const int K  = (li == 0) ? FIN : DIM;
        const int KS = (li == 0) ? 3 : 4;
        f32x4 acc[2][2];
        #pragma unroll
        for (int mt = 0; mt < 2; ++mt)
          #pragma unroll
          for (int nt = 0; nt < 2; ++nt)
            acc[mt][nt] = (f32x4){0.f,0.f,0.f,0.f};
        for (int ks = 0; ks < KS; ++ks) {
          const int k0 = ks*32 + g4*8;
          short8 ah[2], al[2], bh[2], bl[2];
          #pragma unroll
          for (int mt = 0; mt < 2; ++mt) {
            f32x4 va = *(const f32x4*)&sm.x[mt*16 + r0][k0];
            f32x4 vb = *(const f32x4*)&sm.x[mt*16 + r0][k0+4];
            split8(va, vb, ah[mt], al[mt]);
          }
          #pragma unroll
          for (int nt = 0; nt < 2; ++nt) {
            const int c = nb + nt*16 + r0;
            f32x4 wa, wb;
            #pragma unroll
            for (int j = 0; j < 4; ++j) {
              int ka = k0 + j, kb = k0 + 4 + j;
              wa[j] = (ka < K) ? W[(size_t)ka*DIM + c] : 0.f;
              wb[j] = (kb < K) ? W[(size_t)kb*DIM + c] : 0.f;
            }
            split8(wa, wb, bh[nt], bl[nt]);
          }
          #pragma unroll
          for (int mt = 0; mt < 2; ++mt)
            #pragma unroll
            for (int nt = 0; nt < 2; ++nt) {
              acc[mt][nt] = __builtin_amdgcn_mfma_f32_16x16x32_bf16(ah[mt], bh[nt], acc[mt][nt], 0,0,0);
              acc[mt][nt] = __builtin_amdgcn_mfma_f32_16x16x32_bf16(ah[mt], bl[nt], acc[mt][nt], 0,0,0);
              acc[mt][nt] = __builtin_amdgcn_mfma_f32_16x16x32_bf16(al[mt], bh[nt], acc[mt][nt], 0,0,0);
              acc[mt][nt] = __builtin_amdgcn_mfma_f32_16x16x32_bf16(al[mt], bl[nt], acc[mt][nt], 0,0,0);
            }
        }
        // D: col = nb+nt*16+r0, row = mt*16+g4*4+q -> store transposed bf16 hi/lo
        #pragma unroll
        for (int mt = 0; mt < 2; ++mt)
          #pragma unroll
          for (int nt = 0; nt < 2; ++nt) {
            const int c = nb + nt*16 + r0;
            const int row0 = mt*16 + g4*4;
            f32x4 a = acc[mt][nt];
            unsigned h0 = cvtpk(a[0], a[1]), h1 = cvtpk(a[2], a[3]);
            unsigned l0 = cvtpk(a[0]-lo16f(h0), a[1]-hi16f(h0));
            unsigned l1 = cvtpk(a[2]-lo16f(h1), a[3]-hi16f(h1));
            *(uint2*)&sm.h2thi[c][row0] = make_uint2(h0, h1);
            *(uint2*)&sm.h2tlo[c][row0] = make_uint2(l0, l1);
          }
      }
      __syncthreads();

      // ---- C2: a_src/a_dst per (node, head) from h2t; zero Pt ----
      {
        int n = t >> 3, hd = (t >> 2) & 1, j = t & 3;
        const float* as = att_src + ((size_t)li*2 + hd)*64;
        const float* ad = att_dst + ((size_t)li*2 + hd)*64;
        float ss = 0.f, sd = 0.f;
        #pragma unroll
        for (int u2 = 0; u2 < 16; ++u2) {
          int cl = u2*4 + j;
          int c = hd*64 + cl;
          float hv = bf16f(sm.h2thi[c][n]) + bf16f(sm.h2tlo[c][n]);
          ss += hv * as[cl];
          sd += hv * ad[cl];
        }
        ss += __shfl_xor(ss,1); ss += __shfl_xor(ss,2);
        sd += __shfl_xor(sd,1); sd += __shfl_xor(sd,2);
        if (j == 0) { sm.asrc[n][hd] = ss; sm.adst[n][hd] = sd; }
        float* Pz = &sm.uu.a.Pt[0][0][0];
        for (int idx = t; idx < 2*NPG*TS; idx += 256) Pz[idx] = 0.f;
      }
      __syncthreads();

      // ---- C3: alpha = leaky_relu(a_src[s] + a_dst[d]) ----
      if (t < NEL) {
        int s = (t < EPG) ? sm.srcl[t] : (t - EPG);
        int d = (t < EPG) ? sm.dstl[t] : (t - EPG);
        #pragma unroll
        for (int hd = 0; hd < 2; ++hd) {
          float a = sm.asrc[s][hd] + sm.adst[d][hd];
          sm.uu.a.alpha[hd][t] = (a > 0.f) ? a : 0.2f*a;
        }
      }
      __syncthreads();

      // ---- C4a: per-head block max (softmax shift; scale-invariant) ----
      {
        float a0 = (t < NEL) ? sm.uu.a.alpha[0][t] : -1e30f;
        float a1 = (t < NEL) ? sm.uu.a.alpha[1][t] : -1e30f;
        for (int w = 1; w < 64; w <<= 1) {
          a0 = fmaxf(a0, __shfl_xor(a0, w));
          a1 = fmaxf(a1, __shfl_xor(a1, w));
        }
        if ((t & 63) == 0) { sm.wred[t>>6][0] = a0; sm.wred[t>>6][1] = a1; }
      }
      __syncthreads();
      if (t < 2) {
        sm.mh[t] = fmaxf(fmaxf(sm.wred[0][t], sm.wred[1][t]),
                         fmaxf(sm.wred[2][t], sm.wred[3][t]));
      }
      __syncthreads();

      // ---- C4b: scatter exp into Pt[hd][dst][src] ----
      if (t < NEL) {
        int s = (t < EPG) ? sm.srcl[t] : (t - EPG);
        int d = (t < EPG) ? sm.dstl[t] : (t - EPG);
        float e0 = expf(sm.uu.a.alpha[0][t] - sm.mh[0]);
        float e1 = expf(sm.uu.a.alpha[1][t] - sm.mh[1]);
        atomicAdd(&sm.uu.a.Pt[0][d][s], e0);
        atomicAdd(&sm.uu.a.Pt[1][d][s], e1);
      }
      __syncthreads();

      // ---- C4c: den[d][hd] = 1/(row-sum + eps) ----
      if (t < 64) {
        int d = t & 31, hd = t >> 5;
        float s = 0.f;
        #pragma unroll
        for (int s4 = 0; s4 < NPG; s4 += 4) {
          f32x4 v = *(const f32x4*)&sm.uu.a.Pt[hd][d][s4];
          s += v[0] + v[1] + v[2] + v[3];
        }
        sm.den[d][hd] = 1.f / (s + 1e-16f);
      }
      __syncthreads();

      // ---- C4d: P' = Pt * dinv -> bf16 hi/lo, converted in place (reg-staged) ----
      {
        int hd = t >> 7, r = (t >> 2) & 31, s0 = (t & 3) * 8;
        f32x4 pa = *(const f32x4*)&sm.uu.a.Pt[hd][r][s0];
        f32x4 pb = *(const f32x4*)&sm.uu.a.Pt[hd][r][s0+4];
        float dv = sm.den[r][hd];
        #pragma unroll
        for (int q = 0; q < 4; ++q) { pa[q] *= dv; pb[q] *= dv; }
        __syncthreads();   // all reads of f32 Pt done before u16 overwrite
        unsigned short* Pu = (unsigned short*)&sm.uu.a.Pt[0][0][0];
        const int LO = 2*NPG*TS;
        int base = (hd*NPG + r)*TS + s0;
        unsigned h0 = cvtpk(pa[0], pa[1]), h1 = cvtpk(pa[2], pa[3]);
        unsigned h2_ = cvtpk(pb[0], pb[1]), h3 = cvtpk(pb[2], pb[3]);
        unsigned l0 = cvtpk(pa[0]-lo16f(h0), pa[1]-hi16f(h0));
        unsigned l1 = cvtpk(pa[2]-lo16f(h1), pa[3]-hi16f(h1));
        unsigned l2 = cvtpk(pb[0]-lo16f(h2_), pb[1]-hi16f(h2_));
        unsigned l3 = cvtpk(pb[2]-lo16f(h3), pb[3]-hi16f(h3));
        *(uint2*)(Pu + base)     = make_uint2(h0, h1);
        *(uint2*)(Pu + base + 4) = make_uint2(h2_, h3);
        *(uint2*)(Pu + LO + base)     = make_uint2(l0, l1);
        *(uint2*)(Pu + LO + base + 4) = make_uint2(l2, l3);
      }
      __syncthreads();

      // ---- C5: x = P' @ h2 + bias via MFMA (3 cross terms) ----
      {
        const unsigned short* Pu = (const unsigned short*)&sm.uu.a.Pt[0][0][0];
        const int LO = 2*NPG*TS;
        const int k0 = g4*8;
        f32x4 acc[2][2];
        #pragma unroll
        for (int mt = 0; mt < 2; ++mt)
          #pragma unroll
          for (int nt = 0; nt < 2; ++nt)
            acc[mt][nt] = (f32x4){0.f,0.f,0.f,0.f};
        short8 Ah[2], Al[2], Bh[2], Bl[2];
        #pragma unroll
        for (int mt = 0; mt < 2; ++mt) {
          int base = (hdw*NPG + mt*16 + r0)*TS + k0;
          Ah[mt] = ld8(Pu + base);
          Al[mt] = ld8(Pu + LO + base);
        }
        #pragma unroll
        for (int nt = 0; nt < 2; ++nt) {
          const int c = nb + nt*16 + r0;
          Bh[nt] = ld8(&sm.h2thi[c][k0]);
          Bl[nt] = ld8(&sm.h2tlo[c][k0]);
        }
        #pragma unroll
        for (int mt = 0; mt < 2; ++mt)
          #pragma unroll
          for (int nt = 0; nt < 2; ++nt) {
            acc[mt][nt] = __builtin_amdgcn_mfma_f32_16x16x32_bf16(Ah[mt], Bh[nt], acc[mt][nt], 0,0,0);
            acc[mt][nt] = __builtin_amdgcn_mfma_f32_16x16x32_bf16(Ah[mt], Bl[nt], acc[mt][nt], 0,0,0);
            acc[mt][nt] = __builtin_amdgcn_mfma_f32_16x16x32_bf16(Al[mt], Bh[nt], acc[mt][nt], 0,0,0);
          }
        #pragma unroll
        for (int nt = 0; nt < 2; ++nt) {
          const int c = nb + nt*16 + r0;
          float bc = gat_b[(size_t)li*DIM + c];
          #pragma unroll
          for (int mt = 0; mt < 2; ++mt)
            #pragma unroll
            for (int q = 0; q < 4; ++q)
              sm.x[mt*16 + g4*4 + q][c] = acc[mt][nt][q] + bc;
        }
      }
      __syncthreads();

      // ---- C6a: p = x.rw, q = x.root_w per node; zero sacc ----
      {
        int n = t >> 3, j = t & 7;
        const float* rw = srw   + (size_t)li*DIM;
        const float* ro = sroot + (size_t)li*DIM;
        float p = 0.f, q = 0.f;
        #pragma unroll
        for (int u2 = 0; u2 < 16; ++u2) {
          int c = u2*8 + j;
          float xv = sm.x[n][c];
          p += xv * rw[c];
          q += xv * ro[c];
        }
        for (int w = 1; w < 8; w <<= 1) { p += __shfl_xor(p,w); q += __shfl_xor(q,w); }
        if (j == 0) { sm.pl[n] = p; sm.ql[n] = q; }
        if (t < NPG) sm.sacc[t] = 0.f;
      }
      __syncthreads();

      // ---- C6b-1: scatter aggr scores ----
      if (t < EPG) atomicAdd(&sm.sacc[sm.dstl[t]], sm.pl[sm.srcl[t]]);
      __syncthreads();

      // ---- C6b-2: per-graph softmax over 32 nodes ----
      if (t < NPG) {
        float s = sm.sacc[t] + srb[li] + sm.ql[t];
        float m = s;
        for (int w = 1; w < 32; w <<= 1) m = fmaxf(m, __shfl_xor(m, w));
        float ex = expf(s - m);
        float dn = ex;
        for (int w = 1; w < 32; w <<= 1) dn += __shfl_xor(dn, w);
        sm.sval[t] = ex / (dn + 1e-16f);
      }
      __syncthreads();

      // ---- C6c: repr[c] = sum_n x[n][c]*sval[n] ----
      if (t < DIM) {
        float a = 0.f;
        for (int n = 0; n < NPG; ++n) a += sm.x[n][t] * sm.sval[n];
        sm.repr[side][li][t] = a;
      }
      __syncthreads();

      // ---- C7: x = elu(layernorm(x)) (skipped for last layer) ----
      if (li < NB-1) {
        int n = t >> 3, j = t & 7;
        float s = 0.f, s2 = 0.f;
        #pragma unroll
        for (int u2 = 0; u2 < 16; ++u2) {
          float v = sm.x[n][u2*8 + j];
          s += v; s2 += v*v;
        }
        for (int w = 1; w < 8; w <<= 1) { s += __shfl_xor(s,w); s2 += __shfl_xor(s2,w); }
        float mu  = s * (1.f/DIM);
        float var = s2 * (1.f/DIM) - mu*mu;
        float inv = rsqrtf(var + 1e-5f);
        const float* wv = nw  + (size_t)li*DIM;
        const float* bv = nb2 + (size_t)li*DIM;
        #pragma unroll
        for (int u2 = 0; u2 < 16; ++u2) {
          int c = u2*8 + j;
          float v = (sm.x[n][c] - mu) * inv * wv[c] + bv[c];
          sm.x[n][c] = (v > 0.f) ? v : expm1f(v);
        }
        __syncthreads();
      }
    }  // layer loop
  }  // side loop

  // ---- F1: keys = rh @ wk, queries = rt @ wq ----
  {
    int i2 = t >> 6, k = t & 63;
    float ak = 0.f, aq = 0.f;
    for (int d = 0; d < DIM; ++d) {
      ak += sm.repr[0][i2][d] * wkm[(size_t)d*DK + k];
      aq += sm.repr[1][i2][d] * wqm[(size_t)d*DK + k];
    }
    sm.uu.f.keysl[i2][k] = ak;
    sm.uu.f.querl[i2][k] = aq;
  }
  // ---- F2b: repr norms ----
  {
    int sd = t >> 7, i = (t >> 5) & 3, j2 = t & 31;
    float s = 0.f;
    #pragma unroll
    for (int u2 = 0; u2 < 4; ++u2) {
      float v = sm.repr[sd][i][j2*4+u2];
      s += v*v;
    }
    for (int w = 1; w < 32; w <<= 1) s += __shfl_xor(s, w);
    if (j2 == 0) sm.scl[sd][i] = 1.f / fmaxf(sqrtf(s), 1e-12f);
  }
  __syncthreads();

  // ---- F2: att[i][j] ----
  {
    int pair = t >> 4, kk = t & 15;
    int i = pair >> 2, j = pair & 3;
    float a = 0.f;
    #pragma unroll
    for (int u2 = 0; u2 < 4; ++u2) {
      int k = kk*4+u2;
      a += tanhf(sm.uu.f.keysl[i][k] + sm.uu.f.querl[j][k] + cob[k]) * coa[k];
    }
    for (int w = 1; w < 16; w <<= 1) a += __shfl_xor(a, w);
    if (kk == 0) sm.uu.f.attw[pair] = a;
  }
  // ---- F3: u4[i][:] = repr_h[i] @ r_raw ----
  int rel = rels[g];
  if (t < DIM) {
    const float* rr = rel_emb + (size_t)rel * (DIM*DIM);
    float a0=0.f, a1=0.f, a2=0.f, a3=0.f;
    for (int d = 0; d < DIM; ++d) {
      float rv = rr[(size_t)d*DIM + t];
      a0 += sm.repr[0][0][d] * rv;
      a1 += sm.repr[0][1][d] * rv;
      a2 += sm.repr[0][2][d] * rv;
      a3 += sm.repr[0][3][d] * rv;
    }
    sm.uu.f.u4[0][t]=a0; sm.uu.f.u4[1][t]=a1; sm.uu.f.u4[2][t]=a2; sm.uu.f.u4[3][t]=a3;
  }
  __syncthreads();

  // ---- F4: scores + weighted sum ----
  {
    float rninv = 1.f / fmaxf(rnorm[rel], 1e-12f);
    int pair = t >> 4, kk = t & 15;
    int i = pair >> 2, j = pair & 3;
    float a = 0.f;
    #pragma unroll
    for (int u2 = 0; u2 < 8; ++u2) {
      int e = kk*8+u2;
      a += sm.uu.f.u4[i][e] * sm.repr[1][j][e];
    }
    for (int w = 1; w < 16; w <<= 1) a += __shfl_xor(a, w);
    if (kk == 0)
      sm.uu.f.red[pair] = sm.uu.f.attw[pair] * a * sm.scl[0][i] * sm.scl[1][j] * rninv;
  }
  __syncthreads();
  if (t == 0) {
    float s = 0.f;
    for (int p = 0; p < NB*NB; ++p) s += sm.uu.f.red[p];
    out[g] = s;
  }
}

extern "C" void kernel_launch(void* const* d_in, const int* in_sizes, int n_in,
                              void* d_out, int out_size, void* d_ws, size_t ws_size,
                              hipStream_t stream) {
  const float* xh      = (const float*)d_in[0];
  const float* xt      = (const float*)d_in[1];
  const int*   eh      = (const int*)d_in[2];
  const int*   et      = (const int*)d_in[3];
  // d_in[4] = batch (structurally n>>5; unused)
  const int*   rels    = (const int*)d_in[5];
  const float* W0      = (const float*)d_in[6];
  const float* Wr      = (const float*)d_in[7];
  const float* att_src = (const float*)d_in[8];
  const float* att_dst = (const float*)d_in[9];
  const float* gat_b   = (const float*)d_in[10];
  const float* srw     = (const float*)d_in[11];
  const float* srb     = (const float*)d_in[12];
  const float* sroot   = (const float*)d_in[13];
  const float* nw      = (const float*)d_in[14];
  const float* nb2_    = (const float*)d_in[15];
  const float* inw     = (const float*)d_in[16];
  const float* inb     = (const float*)d_in[17];
  const float* wqm     = (const float*)d_in[18];
  const float* wkm     = (const float*)d_in[19];
  const float* cob     = (const float*)d_in[20];
  const float* coa     = (const float*)d_in[21];
  const float* rel_emb = (const float*)d_in[22];
  float* out   = (float*)d_out;
  float* rnorm = (float*)d_ws;   // 86 floats (proven-good ws usage)

  relnorm_kernel<<<NREL, 256, 0, stream>>>(rel_emb, rnorm);
  ssi_kernel<<<NG, 256, 0, stream>>>(xh, xt, eh, et, rels, W0, Wr, att_src, att_dst,
      gat_b, srw, srb, sroot, nw, nb2_, inw, inb, wqm, wkm, cob, coa, rel_emb,
      rnorm, out);
}

// Round 9
// 1236.389 us; speedup vs baseline: 3.2586x; 1.1589x over previous
//
#include <hip/hip_runtime.h>
#include <math.h>

#define NG 8192          // graphs
#define NPG 32           // nodes per graph
#define NN (NG*NPG)      // 262144 nodes
#define NE (NN*4)        // 1048576 edges per side
#define EPG 128          // edges per graph
#define NEL (EPG+NPG)    // edges + self loops
#define FIN 70
#define DIM 128
#define XS 132           // x row stride in floats
#define TS 36            // h2t / Pt row stride (u16 / f32 units)
#define NB 4
#define DK 64
#define NREL 86

typedef __attribute__((ext_vector_type(8))) short short8;
typedef __attribute__((ext_vector_type(4))) float f32x4;
typedef __attribute__((ext_vector_type(4))) unsigned int u32x4;

__device__ inline unsigned cvtpk(float a, float b) {
  unsigned r;
  asm("v_cvt_pk_bf16_f32 %0, %1, %2" : "=v"(r) : "v"(a), "v"(b));
  return r;   // lo16 = bf16(a), hi16 = bf16(b), RNE
}
__device__ inline float lo16f(unsigned u) { return __uint_as_float(u << 16); }
__device__ inline float hi16f(unsigned u) { return __uint_as_float(u & 0xffff0000u); }
__device__ inline float bf16f(unsigned short h) {
  return __uint_as_float(((unsigned int)h) << 16);
}

// 8 f32 -> hi/lo bf16x8 fragments (2-term split, v = hi + lo + O(2^-17 |v|))
__device__ inline void split8(const f32x4& a, const f32x4& b, short8& hi, short8& lo) {
  u32x4 H, L;
  #pragma unroll
  for (int p = 0; p < 2; ++p) {
    float x0 = a[2*p], x1 = a[2*p+1];
    unsigned h = cvtpk(x0, x1);
    H[p] = h;
    L[p] = cvtpk(x0 - lo16f(h), x1 - hi16f(h));
  }
  #pragma unroll
  for (int p = 0; p < 2; ++p) {
    float x0 = b[2*p], x1 = b[2*p+1];
    unsigned h = cvtpk(x0, x1);
    H[2+p] = h;
    L[2+p] = cvtpk(x0 - lo16f(h), x1 - hi16f(h));
  }
  hi = __builtin_bit_cast(short8, H);
  lo = __builtin_bit_cast(short8, L);
}

// 8 contiguous bf16, 8B-aligned (LDS rows) -> short8 via 2x b64
__device__ inline short8 ld8(const unsigned short* p) {
  union { short8 s; uint2 u[2]; } U;
  U.u[0] = *(const uint2*)p;
  U.u[1] = *(const uint2*)(p + 4);
  return U.s;
}
// 8 contiguous bf16, 16B-aligned (global W planes) -> short8 via b128
__device__ inline short8 ld16B(const unsigned short* p) {
  u32x4 u = *(const u32x4*)p;
  return __builtin_bit_cast(short8, u);
}

struct Smem {
  float x[NPG][XS];               // 16.9KB node features (f32)
  unsigned short h2thi[DIM][TS];  // 9.2KB h2 transposed, bf16 hi: h2thi[c][node]
  unsigned short h2tlo[DIM][TS];  // 9.2KB residual
  union {
    float Pt[2][NPG][TS];         // 9.2KB P'[hd][dst][src]; after C4cd reused as bf16 hi|lo
    struct {                      // final phases
      float keysl[NB][DK];
      float querl[NB][DK];
      float attw[NB*NB];
      float red[NB*NB];
      float u4[4][DIM];           // RESCAL u = repr_h @ r
    } f;
  } uu;
  int   srcl[EPG];
  int   dstl[EPG];
  float asrc[NPG][2];
  float adst[NPG][2];
  float wred[4][2];
  float pl[NPG];
  float ql[NPG];
  float sval[NPG];
  float sacc[NPG];
  float repr[2][NB][DIM];
  float scl[2][NB];
};

__global__ __launch_bounds__(256) void relnorm_kernel(
    const float* __restrict__ re, float* __restrict__ outn) {
  int r = blockIdx.x;
  const float* row = re + (size_t)r * (DIM*DIM);
  float s = 0.f;
  for (int i = threadIdx.x; i < DIM*DIM; i += 256) { float v = row[i]; s += v*v; }
  for (int w = 1; w < 64; w <<= 1) s += __shfl_xor(s, w);
  __shared__ float sred[4];
  if ((threadIdx.x & 63) == 0) sred[threadIdx.x >> 6] = s;
  __syncthreads();
  if (threadIdx.x == 0) outn[r] = sqrtf(sred[0]+sred[1]+sred[2]+sred[3]);
}

// W -> transposed bf16 hi/lo planes in ws: hi[l][c][k], lo[l][c][k]
// (l=0 is W0 zero-padded to K=128). Only launched when ws_size suffices.
__global__ __launch_bounds__(256) void wprep_kernel(
    const float* __restrict__ W0, const float* __restrict__ Wr,
    unsigned short* __restrict__ wsp) {
  int idx = blockIdx.x * 256 + threadIdx.x;   // 4*128*128
  int l = idx >> 14;
  int k = (idx >> 7) & 127;
  int c = idx & 127;
  float v;
  if (l == 0) v = (k < FIN) ? W0[(size_t)k*DIM + c] : 0.f;
  else        v = Wr[(size_t)(l-1)*DIM*DIM + (size_t)k*DIM + c];
  unsigned h = cvtpk(v, 0.f);
  unsigned lo = cvtpk(v - lo16f(h), 0.f);
  int o = (l << 14) + c*128 + k;
  wsp[o] = (unsigned short)h;
  wsp[65536 + o] = (unsigned short)lo;
}

__global__ __launch_bounds__(256, 3) void ssi_kernel(
    const float* __restrict__ xh, const float* __restrict__ xt,
    const int* __restrict__ eh, const int* __restrict__ et,
    const int* __restrict__ rels,
    const float* __restrict__ W0, const float* __restrict__ Wr,
    const unsigned short* __restrict__ wsp,   // nullptr -> in-register W split
    const float* __restrict__ att_src, const float* __restrict__ att_dst,
    const float* __restrict__ gat_b,
    const float* __restrict__ srw, const float* __restrict__ srb,
    const float* __restrict__ sroot,
    const float* __restrict__ nw, const float* __restrict__ nb2,
    const float* __restrict__ inw, const float* __restrict__ inb,
    const float* __restrict__ wqm, const float* __restrict__ wkm,
    const float* __restrict__ cob, const float* __restrict__ coa,
    const float* __restrict__ rel_emb, const float* __restrict__ rnorm,
    float* __restrict__ out)
{
  __shared__ Smem sm;
  const int t = threadIdx.x;
  const int g = blockIdx.x;
  const int n0 = g * NPG;
  const int lw = t & 63;
  const int r0 = lw & 15;        // MFMA row/col lane within 16-tile
  const int g4 = lw >> 4;        // MFMA k-group
  const int nb = (t >> 6) * 32;  // wave's 32-col band
  const int hdw = t >> 7;        // wave's head for C5 (cols 0..63 -> 0, 64..127 -> 1)

  for (int side = 0; side < 2; ++side) {
    const float* xin = side ? xt : xh;
    const int*   ed  = side ? et : eh;

    // ---- load edges (local ids) ----
    if (t < EPG) {
      sm.srcl[t] = ed[g*EPG + t] - n0;
      sm.dstl[t] = ed[NE + g*EPG + t] - n0;
    }
    // ---- input layernorm over FIN=70, zero-pad [70,96) for MFMA k-coverage ----
    {
      int n = t >> 3, j = t & 7;
      float s = 0.f, s2 = 0.f;
      for (int f = j; f < FIN; f += 8) {
        float v = xin[(size_t)(n0+n)*FIN + f];
        s += v; s2 += v*v;
      }
      for (int w = 1; w < 8; w <<= 1) { s += __shfl_xor(s, w); s2 += __shfl_xor(s2, w); }
      float mu  = s * (1.f/FIN);
      float var = s2 * (1.f/FIN) - mu*mu;
      float inv = rsqrtf(var + 1e-5f);
      for (int f = j; f < FIN; f += 8) {
        float v = xin[(size_t)(n0+n)*FIN + f];
        sm.x[n][f] = (v - mu) * inv * inw[f] + inb[f];
      }
      for (int f = FIN + j; f < 96; f += 8) sm.x[n][f] = 0.f;
    }
    __syncthreads();

    for (int li = 0; li < NB; ++li) {
      // ---- C1: h2 = x @ W via MFMA; epilogue stores h2 transposed bf16 hi/lo ----
      {
        const float* W = (li == 0) ? W0 : (Wr + (size_t)(li-1)*DIM*DIM);
        const int K  = (li == 0) ? FIN : DIM;
        const int KS = (li == 0) ? 3 : 4;
        f32x4 acc[2][2];
        #pragma unroll
        for (int mt = 0; mt < 2; ++mt)
          #pragma unroll
          for (int nt = 0; nt < 2; ++nt)
            acc[mt][nt] = (f32x4){0.f,0.f,0.f,0.f};
        for (int ks = 0; ks < KS; ++ks) {
          const int k0 = ks*32 + g4*8;
          short8 ah[2], al[2], bh[2], bl[2];
          #pragma unroll
          for (int mt = 0; mt < 2; ++mt) {
            f32x4 va = *(const f32x4*)&sm.x[mt*16 + r0][k0];
            f32x4 vb = *(const f32x4*)&sm.x[mt*16 + r0][k0+4];
            split8(va, vb, ah[mt], al[mt]);
          }
          if (wsp) {
            const unsigned short* Wh = wsp + (li << 14);
            const unsigned short* Wl = wsp + 65536 + (li << 14);
            #pragma unroll
            for (int nt = 0; nt < 2; ++nt) {
              const int c = nb + nt*16 + r0;
              bh[nt] = ld16B(Wh + c*128 + k0);
              bl[nt] = ld16B(Wl + c*128 + k0);
            }
          } else {
            #pragma unroll
            for (int nt = 0; nt < 2; ++nt) {
              const int c = nb + nt*16 + r0;
              f32x4 wa, wb;
              #pragma unroll
              for (int j = 0; j < 4; ++j) {
                int ka = k0 + j, kb = k0 + 4 + j;
                wa[j] = (ka < K) ? W[(size_t)ka*DIM + c] : 0.f;
                wb[j] = (kb < K) ? W[(size_t)kb*DIM + c] : 0.f;
              }
              split8(wa, wb, bh[nt], bl[nt]);
            }
          }
          #pragma unroll
          for (int mt = 0; mt < 2; ++mt)
            #pragma unroll
            for (int nt = 0; nt < 2; ++nt) {
              acc[mt][nt] = __builtin_amdgcn_mfma_f32_16x16x32_bf16(ah[mt], bh[nt], acc[mt][nt], 0,0,0);
              acc[mt][nt] = __builtin_amdgcn_mfma_f32_16x16x32_bf16(ah[mt], bl[nt], acc[mt][nt], 0,0,0);
              acc[mt][nt] = __builtin_amdgcn_mfma_f32_16x16x32_bf16(al[mt], bh[nt], acc[mt][nt], 0,0,0);
              acc[mt][nt] = __builtin_amdgcn_mfma_f32_16x16x32_bf16(al[mt], bl[nt], acc[mt][nt], 0,0,0);
            }
        }
        // D: col = nb+nt*16+r0, row = mt*16+g4*4+q -> store transposed bf16 hi/lo
        #pragma unroll
        for (int mt = 0; mt < 2; ++mt)
          #pragma unroll
          for (int nt = 0; nt < 2; ++nt) {
            const int c = nb + nt*16 + r0;
            const int row0 = mt*16 + g4*4;
            f32x4 a = acc[mt][nt];
            unsigned h0 = cvtpk(a[0], a[1]), h1 = cvtpk(a[2], a[3]);
            unsigned l0 = cvtpk(a[0]-lo16f(h0), a[1]-hi16f(h0));
            unsigned l1 = cvtpk(a[2]-lo16f(h1), a[3]-hi16f(h1));
            *(uint2*)&sm.h2thi[c][row0] = make_uint2(h0, h1);
            *(uint2*)&sm.h2tlo[c][row0] = make_uint2(l0, l1);
          }
      }
      __syncthreads();

      // ---- C2: a_src/a_dst per (node, head) from h2t; zero Pt ----
      {
        int n = t >> 3, hd = (t >> 2) & 1, j = t & 3;
        const float* as = att_src + ((size_t)li*2 + hd)*64;
        const float* ad = att_dst + ((size_t)li*2 + hd)*64;
        float ss = 0.f, sd = 0.f;
        #pragma unroll
        for (int u2 = 0; u2 < 16; ++u2) {
          int cl = u2*4 + j;
          int c = hd*64 + cl;
          float hv = bf16f(sm.h2thi[c][n]) + bf16f(sm.h2tlo[c][n]);
          ss += hv * as[cl];
          sd += hv * ad[cl];
        }
        ss += __shfl_xor(ss,1); ss += __shfl_xor(ss,2);
        sd += __shfl_xor(sd,1); sd += __shfl_xor(sd,2);
        if (j == 0) { sm.asrc[n][hd] = ss; sm.adst[n][hd] = sd; }
        float* Pz = &sm.uu.Pt[0][0][0];
        for (int idx = t; idx < 2*NPG*TS; idx += 256) Pz[idx] = 0.f;
      }
      __syncthreads();

      // ---- C3+C4a fused: alpha in registers, block max via wred ----
      float al0 = -1e30f, al1 = -1e30f;
      int es = 0, edd = 0;
      if (t < NEL) {
        es  = (t < EPG) ? sm.srcl[t] : (t - EPG);
        edd = (t < EPG) ? sm.dstl[t] : (t - EPG);
        float a0 = sm.asrc[es][0] + sm.adst[edd][0];
        float a1 = sm.asrc[es][1] + sm.adst[edd][1];
        al0 = (a0 > 0.f) ? a0 : 0.2f*a0;
        al1 = (a1 > 0.f) ? a1 : 0.2f*a1;
      }
      {
        float m0 = al0, m1 = al1;
        for (int w = 1; w < 64; w <<= 1) {
          m0 = fmaxf(m0, __shfl_xor(m0, w));
          m1 = fmaxf(m1, __shfl_xor(m1, w));
        }
        if ((t & 63) == 0) { sm.wred[t>>6][0] = m0; sm.wred[t>>6][1] = m1; }
      }
      __syncthreads();

      // ---- C4b: scatter exp into Pt[hd][dst][src] (inline block max) ----
      if (t < NEL) {
        float M0 = fmaxf(fmaxf(sm.wred[0][0], sm.wred[1][0]),
                         fmaxf(sm.wred[2][0], sm.wred[3][0]));
        float M1 = fmaxf(fmaxf(sm.wred[0][1], sm.wred[1][1]),
                         fmaxf(sm.wred[2][1], sm.wred[3][1]));
        atomicAdd(&sm.uu.Pt[0][edd][es], __expf(al0 - M0));
        atomicAdd(&sm.uu.Pt[1][edd][es], __expf(al1 - M1));
      }
      __syncthreads();

      // ---- C4cd fused: den in-register (4-lane reduce), scale, -> bf16 hi/lo ----
      {
        int hd = t >> 7, r = (t >> 2) & 31, s0 = (t & 3) * 8;
        f32x4 pa = *(const f32x4*)&sm.uu.Pt[hd][r][s0];
        f32x4 pb = *(const f32x4*)&sm.uu.Pt[hd][r][s0+4];
        float rs = pa[0]+pa[1]+pa[2]+pa[3]+pb[0]+pb[1]+pb[2]+pb[3];
        rs += __shfl_xor(rs, 1);
        rs += __shfl_xor(rs, 2);
        float dv = 1.f / (rs + 1e-16f);
        #pragma unroll
        for (int q = 0; q < 4; ++q) { pa[q] *= dv; pb[q] *= dv; }
        __syncthreads();   // all f32 Pt reads done before u16 overwrite
        unsigned short* Pu = (unsigned short*)&sm.uu.Pt[0][0][0];
        const int LO = 2*NPG*TS;
        int base = (hd*NPG + r)*TS + s0;
        unsigned h0 = cvtpk(pa[0], pa[1]), h1 = cvtpk(pa[2], pa[3]);
        unsigned h2_ = cvtpk(pb[0], pb[1]), h3 = cvtpk(pb[2], pb[3]);
        unsigned l0 = cvtpk(pa[0]-lo16f(h0), pa[1]-hi16f(h0));
        unsigned l1 = cvtpk(pa[2]-lo16f(h1), pa[3]-hi16f(h1));
        unsigned l2 = cvtpk(pb[0]-lo16f(h2_), pb[1]-hi16f(h2_));
        unsigned l3 = cvtpk(pb[2]-lo16f(h3), pb[3]-hi16f(h3));
        *(uint2*)(Pu + base)     = make_uint2(h0, h1);
        *(uint2*)(Pu + base + 4) = make_uint2(h2_, h3);
        *(uint2*)(Pu + LO + base)     = make_uint2(l0, l1);
        *(uint2*)(Pu + LO + base + 4) = make_uint2(l2, l3);
      }
      __syncthreads();

      // ---- C5: x = P' @ h2 + bias via MFMA (3 cross terms) ----
      {
        const unsigned short* Pu = (const unsigned short*)&sm.uu.Pt[0][0][0];
        const int LO = 2*NPG*TS;
        const int k0 = g4*8;
        f32x4 acc[2][2];
        #pragma unroll
        for (int mt = 0; mt < 2; ++mt)
          #pragma unroll
          for (int nt = 0; nt < 2; ++nt)
            acc[mt][nt] = (f32x4){0.f,0.f,0.f,0.f};
        short8 Ah[2], Al[2], Bh[2], Bl[2];
        #pragma unroll
        for (int mt = 0; mt < 2; ++mt) {
          int base = (hdw*NPG + mt*16 + r0)*TS + k0;
          Ah[mt] = ld8(Pu + base);
          Al[mt] = ld8(Pu + LO + base);
        }
        #pragma unroll
        for (int nt = 0; nt < 2; ++nt) {
          const int c = nb + nt*16 + r0;
          Bh[nt] = ld8(&sm.h2thi[c][k0]);
          Bl[nt] = ld8(&sm.h2tlo[c][k0]);
        }
        #pragma unroll
        for (int mt = 0; mt < 2; ++mt)
          #pragma unroll
          for (int nt = 0; nt < 2; ++nt) {
            acc[mt][nt] = __builtin_amdgcn_mfma_f32_16x16x32_bf16(Ah[mt], Bh[nt], acc[mt][nt], 0,0,0);
            acc[mt][nt] = __builtin_amdgcn_mfma_f32_16x16x32_bf16(Ah[mt], Bl[nt], acc[mt][nt], 0,0,0);
            acc[mt][nt] = __builtin_amdgcn_mfma_f32_16x16x32_bf16(Al[mt], Bh[nt], acc[mt][nt], 0,0,0);
          }
        #pragma unroll
        for (int nt = 0; nt < 2; ++nt) {
          const int c = nb + nt*16 + r0;
          float bc = gat_b[(size_t)li*DIM + c];
          #pragma unroll
          for (int mt = 0; mt < 2; ++mt)
            #pragma unroll
            for (int q = 0; q < 4; ++q)
              sm.x[mt*16 + g4*4 + q][c] = acc[mt][nt][q] + bc;
        }
      }
      __syncthreads();

      // ---- C6a: p = x.rw, q = x.root_w per node; zero sacc ----
      {
        int n = t >> 3, j = t & 7;
        const float* rw = srw   + (size_t)li*DIM;
        const float* ro = sroot + (size_t)li*DIM;
        float p = 0.f, q = 0.f;
        #pragma unroll
        for (int u2 = 0; u2 < 16; ++u2) {
          int c = u2*8 + j;
          float xv = sm.x[n][c];
          p += xv * rw[c];
          q += xv * ro[c];
        }
        for (int w = 1; w < 8; w <<= 1) { p += __shfl_xor(p,w); q += __shfl_xor(q,w); }
        if (j == 0) { sm.pl[n] = p; sm.ql[n] = q; }
        if (t < NPG) sm.sacc[t] = 0.f;
      }
      __syncthreads();

      // ---- C6b-1: scatter aggr scores ----
      if (t < EPG) atomicAdd(&sm.sacc[sm.dstl[t]], sm.pl[sm.srcl[t]]);
      __syncthreads();

      // ---- C6b-2: per-graph softmax over 32 nodes ----
      if (t < NPG) {
        float s = sm.sacc[t] + srb[li] + sm.ql[t];
        float m = s;
        for (int w = 1; w < 32; w <<= 1) m = fmaxf(m, __shfl_xor(m, w));
        float ex = __expf(s - m);
        float dn = ex;
        for (int w = 1; w < 32; w <<= 1) dn += __shfl_xor(dn, w);
        sm.sval[t] = ex / (dn + 1e-16f);
      }
      __syncthreads();

      // ---- C6c: repr[c] = sum_n x[n][c]*sval[n] ----
      if (t < DIM) {
        float a = 0.f;
        #pragma unroll 8
        for (int n = 0; n < NPG; ++n) a += sm.x[n][t] * sm.sval[n];
        sm.repr[side][li][t] = a;
      }
      __syncthreads();

      // ---- C7: x = elu(layernorm(x)) (skipped for last layer) ----
      if (li < NB-1) {
        int n = t >> 3, j = t & 7;
        float s = 0.f, s2 = 0.f;
        #pragma unroll
        for (int u2 = 0; u2 < 16; ++u2) {
          float v = sm.x[n][u2*8 + j];
          s += v; s2 += v*v;
        }
        for (int w = 1; w < 8; w <<= 1) { s += __shfl_xor(s,w); s2 += __shfl_xor(s2,w); }
        float mu  = s * (1.f/DIM);
        float var = s2 * (1.f/DIM) - mu*mu;
        float inv = rsqrtf(var + 1e-5f);
        const float* wv = nw  + (size_t)li*DIM;
        const float* bv = nb2 + (size_t)li*DIM;
        #pragma unroll
        for (int u2 = 0; u2 < 16; ++u2) {
          int c = u2*8 + j;
          float v = (sm.x[n][c] - mu) * inv * wv[c] + bv[c];
          sm.x[n][c] = (v > 0.f) ? v : (__expf(v) - 1.f);
        }
        __syncthreads();
      }
    }  // layer loop
  }  // side loop

  // ---- F1: keys = rh @ wk, queries = rt @ wq ----
  {
    int i2 = t >> 6, k = t & 63;
    float ak = 0.f, aq = 0.f;
    for (int d = 0; d < DIM; ++d) {
      ak += sm.repr[0][i2][d] * wkm[(size_t)d*DK + k];
      aq += sm.repr[1][i2][d] * wqm[(size_t)d*DK + k];
    }
    sm.uu.f.keysl[i2][k] = ak;
    sm.uu.f.querl[i2][k] = aq;
  }
  // ---- F2b: repr norms ----
  {
    int sd = t >> 7, i = (t >> 5) & 3, j2 = t & 31;
    float s = 0.f;
    #pragma unroll
    for (int u2 = 0; u2 < 4; ++u2) {
      float v = sm.repr[sd][i][j2*4+u2];
      s += v*v;
    }
    for (int w = 1; w < 32; w <<= 1) s += __shfl_xor(s, w);
    if (j2 == 0) sm.scl[sd][i] = 1.f / fmaxf(sqrtf(s), 1e-12f);
  }
  __syncthreads();

  // ---- F2: att[i][j] ----
  {
    int pair = t >> 4, kk = t & 15;
    int i = pair >> 2, j = pair & 3;
    float a = 0.f;
    #pragma unroll
    for (int u2 = 0; u2 < 4; ++u2) {
      int k = kk*4+u2;
      a += tanhf(sm.uu.f.keysl[i][k] + sm.uu.f.querl[j][k] + cob[k]) * coa[k];
    }
    for (int w = 1; w < 16; w <<= 1) a += __shfl_xor(a, w);
    if (kk == 0) sm.uu.f.attw[pair] = a;
  }
  // ---- F3: u4[i][:] = repr_h[i] @ r_raw ----
  int rel = rels[g];
  if (t < DIM) {
    const float* rr = rel_emb + (size_t)rel * (DIM*DIM);
    float a0=0.f, a1=0.f, a2=0.f, a3=0.f;
    for (int d = 0; d < DIM; ++d) {
      float rv = rr[(size_t)d*DIM + t];
      a0 += sm.repr[0][0][d] * rv;
      a1 += sm.repr[0][1][d] * rv;
      a2 += sm.repr[0][2][d] * rv;
      a3 += sm.repr[0][3][d] * rv;
    }
    sm.uu.f.u4[0][t]=a0; sm.uu.f.u4[1][t]=a1; sm.uu.f.u4[2][t]=a2; sm.uu.f.u4[3][t]=a3;
  }
  __syncthreads();

  // ---- F4: scores + weighted sum ----
  {
    float rninv = 1.f / fmaxf(rnorm[rel], 1e-12f);
    int pair = t >> 4, kk = t & 15;
    int i = pair >> 2, j = pair & 3;
    float a = 0.f;
    #pragma unroll
    for (int u2 = 0; u2 < 8; ++u2) {
      int e = kk*8+u2;
      a += sm.uu.f.u4[i][e] * sm.repr[1][j][e];
    }
    for (int w = 1; w < 16; w <<= 1) a += __shfl_xor(a, w);
    if (kk == 0)
      sm.uu.f.red[pair] = sm.uu.f.attw[pair] * a * sm.scl[0][i] * sm.scl[1][j] * rninv;
  }
  __syncthreads();
  if (t == 0) {
    float s = 0.f;
    for (int p = 0; p < NB*NB; ++p) s += sm.uu.f.red[p];
    out[g] = s;
  }
}

extern "C" void kernel_launch(void* const* d_in, const int* in_sizes, int n_in,
                              void* d_out, int out_size, void* d_ws, size_t ws_size,
                              hipStream_t stream) {
  const float* xh      = (const float*)d_in[0];
  const float* xt      = (const float*)d_in[1];
  const int*   eh      = (const int*)d_in[2];
  const int*   et      = (const int*)d_in[3];
  // d_in[4] = batch (structurally n>>5; unused)
  const int*   rels    = (const int*)d_in[5];
  const float* W0      = (const float*)d_in[6];
  const float* Wr      = (const float*)d_in[7];
  const float* att_src = (const float*)d_in[8];
  const float* att_dst = (const float*)d_in[9];
  const float* gat_b   = (const float*)d_in[10];
  const float* srw     = (const float*)d_in[11];
  const float* srb     = (const float*)d_in[12];
  const float* sroot   = (const float*)d_in[13];
  const float* nw      = (const float*)d_in[14];
  const float* nb2_    = (const float*)d_in[15];
  const float* inw     = (const float*)d_in[16];
  const float* inb     = (const float*)d_in[17];
  const float* wqm     = (const float*)d_in[18];
  const float* wkm     = (const float*)d_in[19];
  const float* cob     = (const float*)d_in[20];
  const float* coa     = (const float*)d_in[21];
  const float* rel_emb = (const float*)d_in[22];
  float* out   = (float*)d_out;
  float* rnorm = (float*)d_ws;   // 86 floats (proven-good ws usage)

  // Guarded W-split precompute: rnorm in [0,344); W planes at +512 (2*128KB).
  const size_t WS_NEED = 512 + 2 * 65536 * sizeof(unsigned short);
  const unsigned short* wsp = nullptr;
  relnorm_kernel<<<NREL, 256, 0, stream>>>(rel_emb, rnorm);
  if (ws_size >= WS_NEED) {
    unsigned short* w = (unsigned short*)((char*)d_ws + 512);
    wprep_kernel<<<256, 256, 0, stream>>>(W0, Wr, w);
    wsp = w;
  }
  ssi_kernel<<<NG, 256, 0, stream>>>(xh, xt, eh, et, rels, W0, Wr, wsp,
      att_src, att_dst, gat_b, srw, srb, sroot, nw, nb2_, inw, inb,
      wqm, wkm, cob, coa, rel_emb, rnorm, out);
}

// Round 10
// 1230.488 us; speedup vs baseline: 3.2742x; 1.0048x over previous
//
#include <hip/hip_runtime.h>
#include <math.h>

#define NG 8192          // graphs
#define NPG 32           // nodes per graph
#define NN (NG*NPG)      // 262144 nodes
#define NE (NN*4)        // 1048576 edges per side
#define EPG 128          // edges per graph
#define NEL (EPG+NPG)    // edges + self loops
#define FIN 70
#define DIM 128
#define XS 132           // x row stride in floats
#define TS 36            // h2t / Pt row stride (u16 / f32 units)
#define NB 4
#define DK 64
#define NREL 86

typedef __attribute__((ext_vector_type(8))) short short8;
typedef __attribute__((ext_vector_type(4))) float f32x4;
typedef __attribute__((ext_vector_type(4))) unsigned int u32x4;

__device__ inline unsigned cvtpk(float a, float b) {
  unsigned r;
  asm("v_cvt_pk_bf16_f32 %0, %1, %2" : "=v"(r) : "v"(a), "v"(b));
  return r;   // lo16 = bf16(a), hi16 = bf16(b), RNE
}
__device__ inline float lo16f(unsigned u) { return __uint_as_float(u << 16); }
__device__ inline float hi16f(unsigned u) { return __uint_as_float(u & 0xffff0000u); }
__device__ inline float bf16f(unsigned short h) {
  return __uint_as_float(((unsigned int)h) << 16);
}

// 8 f32 -> hi/lo bf16x8 fragments (2-term split, v = hi + lo + O(2^-17 |v|))
__device__ inline void split8(const f32x4& a, const f32x4& b, short8& hi, short8& lo) {
  u32x4 H, L;
  #pragma unroll
  for (int p = 0; p < 2; ++p) {
    float x0 = a[2*p], x1 = a[2*p+1];
    unsigned h = cvtpk(x0, x1);
    H[p] = h;
    L[p] = cvtpk(x0 - lo16f(h), x1 - hi16f(h));
  }
  #pragma unroll
  for (int p = 0; p < 2; ++p) {
    float x0 = b[2*p], x1 = b[2*p+1];
    unsigned h = cvtpk(x0, x1);
    H[2+p] = h;
    L[2+p] = cvtpk(x0 - lo16f(h), x1 - hi16f(h));
  }
  hi = __builtin_bit_cast(short8, H);
  lo = __builtin_bit_cast(short8, L);
}

// 8 contiguous bf16, 8B-aligned (LDS rows) -> short8 via 2x b64
__device__ inline short8 ld8(const unsigned short* p) {
  union { short8 s; uint2 u[2]; } U;
  U.u[0] = *(const uint2*)p;
  U.u[1] = *(const uint2*)(p + 4);
  return U.s;
}
// 8 contiguous bf16, 16B-aligned (global W planes) -> short8 via b128
__device__ inline short8 ld16B(const unsigned short* p) {
  u32x4 u = *(const u32x4*)p;
  return __builtin_bit_cast(short8, u);
}

struct Smem {
  float x[NPG][XS];               // 16.9KB node features (f32)
  unsigned short h2thi[DIM][TS];  // 9.2KB h2 transposed, bf16 hi: h2thi[c][node]
  unsigned short h2tlo[DIM][TS];  // 9.2KB residual
  union {
    float Pt[2][NPG][TS];         // 9.2KB P'[hd][dst][src]; after C4cd reused as bf16 hi|lo
    struct {                      // final phases
      float keysl[NB][DK];
      float querl[NB][DK];
      float attw[NB*NB];
      float red[NB*NB];
      float u4[4][DIM];           // RESCAL u = repr_h @ r
    } f;
  } uu;
  int   srcl[EPG];
  int   dstl[EPG];
  float asrc[NPG][2];
  float adst[NPG][2];
  float wred[4][2];
  float pl[NPG];
  float ql[NPG];
  float hrq[4][NPG];              // FAST: hr0,hr1,hq0,hq1 per node
  float pqp[2][NPG];              // FAST: p partial per (head,node)
  float pqq[2][NPG];              // FAST: q partial per (head,node)
  float cbl[NB];                  // FAST: gat_b . srw per layer
  float sval[NPG];
  float sacc[NPG];
  float repr[2][NB][DIM];
  float scl[2][NB];
};

__global__ __launch_bounds__(256) void relnorm_kernel(
    const float* __restrict__ re, float* __restrict__ outn) {
  int r = blockIdx.x;
  const float* row = re + (size_t)r * (DIM*DIM);
  float s = 0.f;
  for (int i = threadIdx.x; i < DIM*DIM; i += 256) { float v = row[i]; s += v*v; }
  for (int w = 1; w < 64; w <<= 1) s += __shfl_xor(s, w);
  __shared__ float sred[4];
  if ((threadIdx.x & 63) == 0) sred[threadIdx.x >> 6] = s;
  __syncthreads();
  if (threadIdx.x == 0) outn[r] = sqrtf(sred[0]+sred[1]+sred[2]+sred[3]);
}

// W -> transposed bf16 hi/lo planes in ws: hi[l][c][k], lo[l][c][k]
__global__ __launch_bounds__(256) void wprep_kernel(
    const float* __restrict__ W0, const float* __restrict__ Wr,
    unsigned short* __restrict__ wsp) {
  int idx = blockIdx.x * 256 + threadIdx.x;   // 4*128*128
  int l = idx >> 14;
  int k = (idx >> 7) & 127;
  int c = idx & 127;
  float v;
  if (l == 0) v = (k < FIN) ? W0[(size_t)k*DIM + c] : 0.f;
  else        v = Wr[(size_t)(l-1)*DIM*DIM + (size_t)k*DIM + c];
  unsigned h = cvtpk(v, 0.f);
  unsigned lo = cvtpk(v - lo16f(h), 0.f);
  int o = (l << 14) + c*128 + k;
  wsp[o] = (unsigned short)h;
  wsp[65536 + o] = (unsigned short)lo;
}

// Projected extra columns: wx[li][j][k] = sum_c W[k][c]*v_j[c], j in 0..7:
// 0:as_h0 1:ad_h0 2:as_h1 3:ad_h1 4:rw_h0 5:rw_h1 6:ro_h0 7:ro_h1; j>=8 zero.
__global__ __launch_bounds__(128) void wxprep_kernel(
    const float* __restrict__ W0, const float* __restrict__ Wr,
    const float* __restrict__ att_src, const float* __restrict__ att_dst,
    const float* __restrict__ srw, const float* __restrict__ sroot,
    unsigned short* __restrict__ wx) {
  int b = blockIdx.x;          // 64 = 4 li * 16 j
  int li = b >> 4, j = b & 15;
  int k = threadIdx.x;         // 0..127
  const int K = (li == 0) ? FIN : DIM;
  float val = 0.f;
  if (j < 8 && k < K) {
    const float* Wrow = (li == 0) ? (W0 + (size_t)k*DIM)
                                  : (Wr + (size_t)(li-1)*DIM*DIM + (size_t)k*DIM);
    const float* v; int c0;
    switch (j) {
      case 0: v = att_src + ((size_t)li*2+0)*64; c0 = 0;  break;
      case 1: v = att_dst + ((size_t)li*2+0)*64; c0 = 0;  break;
      case 2: v = att_src + ((size_t)li*2+1)*64; c0 = 64; break;
      case 3: v = att_dst + ((size_t)li*2+1)*64; c0 = 64; break;
      case 4: v = srw   + (size_t)li*DIM;        c0 = 0;  break;
      case 5: v = srw   + (size_t)li*DIM;        c0 = 64; break;
      case 6: v = sroot + (size_t)li*DIM;        c0 = 0;  break;
      default: v = sroot + (size_t)li*DIM;       c0 = 64; break;
    }
    for (int c = 0; c < 64; ++c) {
      float vc = (j < 4) ? v[c] : v[c0 + c];
      val += Wrow[c0 + c] * vc;
    }
  }
  unsigned h = cvtpk(val, 0.f);
  unsigned lo = cvtpk(val - lo16f(h), 0.f);
  int o = (li << 11) + j*128 + k;
  wx[o] = (unsigned short)h;
  wx[8192 + o] = (unsigned short)lo;
}

template <bool FAST>
__global__ __launch_bounds__(256, 3) void ssi_kernel(
    const float* __restrict__ xh, const float* __restrict__ xt,
    const int* __restrict__ eh, const int* __restrict__ et,
    const int* __restrict__ rels,
    const float* __restrict__ W0, const float* __restrict__ Wr,
    const unsigned short* __restrict__ wsp,   // nullptr -> in-register W split
    const unsigned short* __restrict__ wx,    // FAST only
    const float* __restrict__ att_src, const float* __restrict__ att_dst,
    const float* __restrict__ gat_b,
    const float* __restrict__ srw, const float* __restrict__ srb,
    const float* __restrict__ sroot,
    const float* __restrict__ nw, const float* __restrict__ nb2,
    const float* __restrict__ inw, const float* __restrict__ inb,
    const float* __restrict__ wqm, const float* __restrict__ wkm,
    const float* __restrict__ cob, const float* __restrict__ coa,
    const float* __restrict__ rel_emb, const float* __restrict__ rnorm,
    float* __restrict__ out)
{
  __shared__ Smem sm;
  const int t = threadIdx.x;
  const int g = blockIdx.x;
  const int n0 = g * NPG;
  const int lw = t & 63;
  const int r0 = lw & 15;        // MFMA row/col lane within 16-tile
  const int g4 = lw >> 4;        // MFMA k-group
  const int nb = (t >> 6) * 32;  // wave's 32-col band
  const int hdw = t >> 7;        // wave's head for C5

  for (int side = 0; side < 2; ++side) {
    const float* xin = side ? xt : xh;
    const int*   ed  = side ? et : eh;

    // ---- load edges (local ids); FAST: fold cb[li] = gat_b.srw (side 0) ----
    if (t < EPG) {
      sm.srcl[t] = ed[g*EPG + t] - n0;
      sm.dstl[t] = ed[NE + g*EPG + t] - n0;
    }
    if (FAST && side == 0 && t >= 128) {
      int li2 = (t-128) >> 5, ln = (t-128) & 31;
      float s_ = 0.f;
      #pragma unroll
      for (int m = 0; m < 4; ++m) {
        int c = ln + 32*m;
        s_ += gat_b[(size_t)li2*DIM + c] * srw[(size_t)li2*DIM + c];
      }
      for (int w = 1; w < 32; w <<= 1) s_ += __shfl_xor(s_, w);
      if (ln == 0) sm.cbl[li2] = s_;
    }
    // ---- input layernorm over FIN=70, zero-pad [70,96) ----
    {
      int n = t >> 3, j = t & 7;
      float s = 0.f, s2 = 0.f;
      for (int f = j; f < FIN; f += 8) {
        float v = xin[(size_t)(n0+n)*FIN + f];
        s += v; s2 += v*v;
      }
      for (int w = 1; w < 8; w <<= 1) { s += __shfl_xor(s, w); s2 += __shfl_xor(s2, w); }
      float mu  = s * (1.f/FIN);
      float var = s2 * (1.f/FIN) - mu*mu;
      float inv = rsqrtf(var + 1e-5f);
      for (int f = j; f < FIN; f += 8) {
        float v = xin[(size_t)(n0+n)*FIN + f];
        sm.x[n][f] = (v - mu) * inv * inw[f] + inb[f];
      }
      for (int f = FIN + j; f < 96; f += 8) sm.x[n][f] = 0.f;
    }
    __syncthreads();

    for (int li = 0; li < NB; ++li) {
      // ---- C1: h2 = x @ W via MFMA; epilogue stores h2 transposed bf16 hi/lo.
      //      FAST: wave 0 also computes the projected extra tile ->
      //      asrc/adst (4 cols) and hr/hq head-split (4 cols). ----
      {
        const float* W = (li == 0) ? W0 : (Wr + (size_t)(li-1)*DIM*DIM);
        const int K  = (li == 0) ? FIN : DIM;
        const int KS = (li == 0) ? 3 : 4;
        f32x4 acc[2][2];
        f32x4 accx[2];
        #pragma unroll
        for (int mt = 0; mt < 2; ++mt) {
          accx[mt] = (f32x4){0.f,0.f,0.f,0.f};
          #pragma unroll
          for (int nt = 0; nt < 2; ++nt)
            acc[mt][nt] = (f32x4){0.f,0.f,0.f,0.f};
        }
        const unsigned short* Wxh = FAST ? (wx + (li << 11)) : nullptr;
        const unsigned short* Wxl = FAST ? (wx + 8192 + (li << 11)) : nullptr;
        for (int ks = 0; ks < KS; ++ks) {
          const int k0 = ks*32 + g4*8;
          short8 ah[2], al[2], bh[2], bl[2];
          #pragma unroll
          for (int mt = 0; mt < 2; ++mt) {
            f32x4 va = *(const f32x4*)&sm.x[mt*16 + r0][k0];
            f32x4 vb = *(const f32x4*)&sm.x[mt*16 + r0][k0+4];
            split8(va, vb, ah[mt], al[mt]);
          }
          if (wsp) {
            const unsigned short* Wh = wsp + (li << 14);
            const unsigned short* Wl = wsp + 65536 + (li << 14);
            #pragma unroll
            for (int nt = 0; nt < 2; ++nt) {
              const int c = nb + nt*16 + r0;
              bh[nt] = ld16B(Wh + c*128 + k0);
              bl[nt] = ld16B(Wl + c*128 + k0);
            }
          } else {
            #pragma unroll
            for (int nt = 0; nt < 2; ++nt) {
              const int c = nb + nt*16 + r0;
              f32x4 wa, wb;
              #pragma unroll
              for (int j = 0; j < 4; ++j) {
                int ka = k0 + j, kb = k0 + 4 + j;
                wa[j] = (ka < K) ? W[(size_t)ka*DIM + c] : 0.f;
                wb[j] = (kb < K) ? W[(size_t)kb*DIM + c] : 0.f;
              }
              split8(wa, wb, bh[nt], bl[nt]);
            }
          }
          #pragma unroll
          for (int mt = 0; mt < 2; ++mt)
            #pragma unroll
            for (int nt = 0; nt < 2; ++nt) {
              acc[mt][nt] = __builtin_amdgcn_mfma_f32_16x16x32_bf16(ah[mt], bh[nt], acc[mt][nt], 0,0,0);
              acc[mt][nt] = __builtin_amdgcn_mfma_f32_16x16x32_bf16(ah[mt], bl[nt], acc[mt][nt], 0,0,0);
              acc[mt][nt] = __builtin_amdgcn_mfma_f32_16x16x32_bf16(al[mt], bh[nt], acc[mt][nt], 0,0,0);
              acc[mt][nt] = __builtin_amdgcn_mfma_f32_16x16x32_bf16(al[mt], bl[nt], acc[mt][nt], 0,0,0);
            }
          if (FAST && t < 64) {   // wave 0: projected extra tile
            short8 bxh = ld16B(Wxh + r0*128 + k0);
            short8 bxl = ld16B(Wxl + r0*128 + k0);
            #pragma unroll
            for (int mt = 0; mt < 2; ++mt) {
              accx[mt] = __builtin_amdgcn_mfma_f32_16x16x32_bf16(ah[mt], bxh, accx[mt], 0,0,0);
              accx[mt] = __builtin_amdgcn_mfma_f32_16x16x32_bf16(ah[mt], bxl, accx[mt], 0,0,0);
              accx[mt] = __builtin_amdgcn_mfma_f32_16x16x32_bf16(al[mt], bxh, accx[mt], 0,0,0);
              accx[mt] = __builtin_amdgcn_mfma_f32_16x16x32_bf16(al[mt], bxl, accx[mt], 0,0,0);
            }
          }
        }
        // D: col = nb+nt*16+r0, row = mt*16+g4*4+q -> store transposed bf16 hi/lo
        #pragma unroll
        for (int mt = 0; mt < 2; ++mt)
          #pragma unroll
          for (int nt = 0; nt < 2; ++nt) {
            const int c = nb + nt*16 + r0;
            const int row0 = mt*16 + g4*4;
            f32x4 a = acc[mt][nt];
            unsigned h0 = cvtpk(a[0], a[1]), h1 = cvtpk(a[2], a[3]);
            unsigned l0 = cvtpk(a[0]-lo16f(h0), a[1]-hi16f(h0));
            unsigned l1 = cvtpk(a[2]-lo16f(h1), a[3]-hi16f(h1));
            *(uint2*)&sm.h2thi[c][row0] = make_uint2(h0, h1);
            *(uint2*)&sm.h2tlo[c][row0] = make_uint2(l0, l1);
          }
        if (FAST && t < 64 && r0 < 8) {
          #pragma unroll
          for (int mt = 0; mt < 2; ++mt)
            #pragma unroll
            for (int q = 0; q < 4; ++q) {
              int n = mt*16 + g4*4 + q;
              float v = accx[mt][q];
              switch (r0) {
                case 0: sm.asrc[n][0] = v; break;
                case 1: sm.adst[n][0] = v; break;
                case 2: sm.asrc[n][1] = v; break;
                case 3: sm.adst[n][1] = v; break;
                default: sm.hrq[r0-4][n] = v;
              }
            }
        }
      }
      __syncthreads();

      // ---- C2 (non-FAST only): a_src/a_dst from h2t; zero Pt ----
      if (!FAST) {
        int n = t >> 3, hd = (t >> 2) & 1, j = t & 3;
        const float* as = att_src + ((size_t)li*2 + hd)*64;
        const float* ad = att_dst + ((size_t)li*2 + hd)*64;
        float ss = 0.f, sd = 0.f;
        #pragma unroll
        for (int u2 = 0; u2 < 16; ++u2) {
          int cl = u2*4 + j;
          int c = hd*64 + cl;
          float hv = bf16f(sm.h2thi[c][n]) + bf16f(sm.h2tlo[c][n]);
          ss += hv * as[cl];
          sd += hv * ad[cl];
        }
        ss += __shfl_xor(ss,1); ss += __shfl_xor(ss,2);
        sd += __shfl_xor(sd,1); sd += __shfl_xor(sd,2);
        if (j == 0) { sm.asrc[n][hd] = ss; sm.adst[n][hd] = sd; }
        float* Pz = &sm.uu.Pt[0][0][0];
        for (int idx = t; idx < 2*NPG*TS; idx += 256) Pz[idx] = 0.f;
        __syncthreads();
      }

      // ---- C3+C4a fused: alpha in registers + block max; FAST also zeros Pt ----
      float al0 = -1e30f, al1 = -1e30f;
      int es = 0, edd = 0;
      if (t < NEL) {
        es  = (t < EPG) ? sm.srcl[t] : (t - EPG);
        edd = (t < EPG) ? sm.dstl[t] : (t - EPG);
        float a0 = sm.asrc[es][0] + sm.adst[edd][0];
        float a1 = sm.asrc[es][1] + sm.adst[edd][1];
        al0 = (a0 > 0.f) ? a0 : 0.2f*a0;
        al1 = (a1 > 0.f) ? a1 : 0.2f*a1;
      }
      if (FAST) {
        float* Pz = &sm.uu.Pt[0][0][0];
        for (int idx = t; idx < 2*NPG*TS; idx += 256) Pz[idx] = 0.f;
      }
      {
        float m0 = al0, m1 = al1;
        for (int w = 1; w < 64; w <<= 1) {
          m0 = fmaxf(m0, __shfl_xor(m0, w));
          m1 = fmaxf(m1, __shfl_xor(m1, w));
        }
        if ((t & 63) == 0) { sm.wred[t>>6][0] = m0; sm.wred[t>>6][1] = m1; }
      }
      __syncthreads();

      // ---- C4b: scatter exp into Pt[hd][dst][src]; FAST zeros sacc here ----
      if (t < NEL) {
        float M0 = fmaxf(fmaxf(sm.wred[0][0], sm.wred[1][0]),
                         fmaxf(sm.wred[2][0], sm.wred[3][0]));
        float M1 = fmaxf(fmaxf(sm.wred[0][1], sm.wred[1][1]),
                         fmaxf(sm.wred[2][1], sm.wred[3][1]));
        atomicAdd(&sm.uu.Pt[0][edd][es], __expf(al0 - M0));
        atomicAdd(&sm.uu.Pt[1][edd][es], __expf(al1 - M1));
      } else if (FAST && t < NEL + NPG) {
        sm.sacc[t - NEL] = 0.f;
      }
      __syncthreads();

      // ---- C4cd fused: den in-register, scale, FAST: p/q from P' regs, -> bf16 ----
      {
        int hd = t >> 7, r = (t >> 2) & 31, s0 = (t & 3) * 8;
        f32x4 pa = *(const f32x4*)&sm.uu.Pt[hd][r][s0];
        f32x4 pb = *(const f32x4*)&sm.uu.Pt[hd][r][s0+4];
        float rs = pa[0]+pa[1]+pa[2]+pa[3]+pb[0]+pb[1]+pb[2]+pb[3];
        rs += __shfl_xor(rs, 1);
        rs += __shfl_xor(rs, 2);
        float dv = 1.f / (rs + 1e-16f);
        #pragma unroll
        for (int q = 0; q < 4; ++q) { pa[q] *= dv; pb[q] *= dv; }
        if (FAST) {   // p/q partials for this (head, dst-row)
          f32x4 h0 = *(const f32x4*)&sm.hrq[hd][s0];
          f32x4 h1 = *(const f32x4*)&sm.hrq[hd][s0+4];
          f32x4 q0 = *(const f32x4*)&sm.hrq[2+hd][s0];
          f32x4 q1 = *(const f32x4*)&sm.hrq[2+hd][s0+4];
          float pp = 0.f, qq = 0.f;
          #pragma unroll
          for (int i = 0; i < 4; ++i) {
            pp += pa[i]*h0[i] + pb[i]*h1[i];
            qq += pa[i]*q0[i] + pb[i]*q1[i];
          }
          pp += __shfl_xor(pp, 1); pp += __shfl_xor(pp, 2);
          qq += __shfl_xor(qq, 1); qq += __shfl_xor(qq, 2);
          if ((t & 3) == 0) { sm.pqp[hd][r] = pp; sm.pqq[hd][r] = qq; }
        }
        __syncthreads();   // all f32 Pt reads done before u16 overwrite
        unsigned short* Pu = (unsigned short*)&sm.uu.Pt[0][0][0];
        const int LO = 2*NPG*TS;
        int base = (hd*NPG + r)*TS + s0;
        unsigned h0 = cvtpk(pa[0], pa[1]), h1 = cvtpk(pa[2], pa[3]);
        unsigned h2_ = cvtpk(pb[0], pb[1]), h3 = cvtpk(pb[2], pb[3]);
        unsigned l0 = cvtpk(pa[0]-lo16f(h0), pa[1]-hi16f(h0));
        unsigned l1 = cvtpk(pa[2]-lo16f(h1), pa[3]-hi16f(h1));
        unsigned l2 = cvtpk(pb[0]-lo16f(h2_), pb[1]-hi16f(h2_));
        unsigned l3 = cvtpk(pb[2]-lo16f(h3), pb[3]-hi16f(h3));
        *(uint2*)(Pu + base)     = make_uint2(h0, h1);
        *(uint2*)(Pu + base + 4) = make_uint2(h2_, h3);
        *(uint2*)(Pu + LO + base)     = make_uint2(l0, l1);
        *(uint2*)(Pu + LO + base + 4) = make_uint2(l2, l3);
      }
      __syncthreads();

      // ---- C5: x = P' @ h2 + bias via MFMA (3 cross terms) ----
      {
        const unsigned short* Pu = (const unsigned short*)&sm.uu.Pt[0][0][0];
        const int LO = 2*NPG*TS;
        const int k0 = g4*8;
        f32x4 acc[2][2];
        #pragma unroll
        for (int mt = 0; mt < 2; ++mt)
          #pragma unroll
          for (int nt = 0; nt < 2; ++nt)
            acc[mt][nt] = (f32x4){0.f,0.f,0.f,0.f};
        short8 Ah[2], Al[2], Bh[2], Bl[2];
        #pragma unroll
        for (int mt = 0; mt < 2; ++mt) {
          int base = (hdw*NPG + mt*16 + r0)*TS + k0;
          Ah[mt] = ld8(Pu + base);
          Al[mt] = ld8(Pu + LO + base);
        }
        #pragma unroll
        for (int nt = 0; nt < 2; ++nt) {
          const int c = nb + nt*16 + r0;
          Bh[nt] = ld8(&sm.h2thi[c][k0]);
          Bl[nt] = ld8(&sm.h2tlo[c][k0]);
        }
        #pragma unroll
        for (int mt = 0; mt < 2; ++mt)
          #pragma unroll
          for (int nt = 0; nt < 2; ++nt) {
            acc[mt][nt] = __builtin_amdgcn_mfma_f32_16x16x32_bf16(Ah[mt], Bh[nt], acc[mt][nt], 0,0,0);
            acc[mt][nt] = __builtin_amdgcn_mfma_f32_16x16x32_bf16(Ah[mt], Bl[nt], acc[mt][nt], 0,0,0);
            acc[mt][nt] = __builtin_amdgcn_mfma_f32_16x16x32_bf16(Al[mt], Bh[nt], acc[mt][nt], 0,0,0);
          }
        #pragma unroll
        for (int nt = 0; nt < 2; ++nt) {
          const int c = nb + nt*16 + r0;
          float bc = gat_b[(size_t)li*DIM + c];
          #pragma unroll
          for (int mt = 0; mt < 2; ++mt)
            #pragma unroll
            for (int q = 0; q < 4; ++q)
              sm.x[mt*16 + g4*4 + q][c] = acc[mt][nt][q] + bc;
        }
      }
      __syncthreads();

      // ---- C6a (non-FAST only): p = x.rw, q = x.root_w per node; zero sacc ----
      if (!FAST) {
        int n = t >> 3, j = t & 7;
        const float* rw = srw   + (size_t)li*DIM;
        const float* ro = sroot + (size_t)li*DIM;
        float p = 0.f, q = 0.f;
        #pragma unroll
        for (int u2 = 0; u2 < 16; ++u2) {
          int c = u2*8 + j;
          float xv = sm.x[n][c];
          p += xv * rw[c];
          q += xv * ro[c];
        }
        for (int w = 1; w < 8; w <<= 1) { p += __shfl_xor(p,w); q += __shfl_xor(q,w); }
        if (j == 0) { sm.pl[n] = p; sm.ql[n] = q; }
        if (t < NPG) sm.sacc[t] = 0.f;
        __syncthreads();
      }

      // ---- C6b-1: scatter aggr scores ----
      if (t < EPG) {
        int s = sm.srcl[t], d = sm.dstl[t];
        float ps;
        if (FAST) ps = sm.pqp[0][s] + sm.pqp[1][s] + sm.cbl[li];
        else      ps = sm.pl[s];
        atomicAdd(&sm.sacc[d], ps);
      }
      __syncthreads();

      // ---- C6b-2: per-graph softmax over 32 nodes ----
      if (t < NPG) {
        float qn = FAST ? (sm.pqq[0][t] + sm.pqq[1][t]) : sm.ql[t];
        float s = sm.sacc[t] + srb[li] + qn;
        float m = s;
        for (int w = 1; w < 32; w <<= 1) m = fmaxf(m, __shfl_xor(m, w));
        float ex = __expf(s - m);
        float dn = ex;
        for (int w = 1; w < 32; w <<= 1) dn += __shfl_xor(dn, w);
        sm.sval[t] = ex / (dn + 1e-16f);
      }
      __syncthreads();

      // ---- C6c: repr[c] = sum_n x[n][c]*sval[n] ----
      if (t < DIM) {
        float a = 0.f;
        #pragma unroll 8
        for (int n = 0; n < NPG; ++n) a += sm.x[n][t] * sm.sval[n];
        sm.repr[side][li][t] = a;
      }
      __syncthreads();

      // ---- C7: x = elu(layernorm(x)) (skipped for last layer) ----
      if (li < NB-1) {
        int n = t >> 3, j = t & 7;
        float s = 0.f, s2 = 0.f;
        #pragma unroll
        for (int u2 = 0; u2 < 16; ++u2) {
          float v = sm.x[n][u2*8 + j];
          s += v; s2 += v*v;
        }
        for (int w = 1; w < 8; w <<= 1) { s += __shfl_xor(s,w); s2 += __shfl_xor(s2,w); }
        float mu  = s * (1.f/DIM);
        float var = s2 * (1.f/DIM) - mu*mu;
        float inv = rsqrtf(var + 1e-5f);
        const float* wv = nw  + (size_t)li*DIM;
        const float* bv = nb2 + (size_t)li*DIM;
        #pragma unroll
        for (int u2 = 0; u2 < 16; ++u2) {
          int c = u2*8 + j;
          float v = (sm.x[n][c] - mu) * inv * wv[c] + bv[c];
          sm.x[n][c] = (v > 0.f) ? v : (__expf(v) - 1.f);
        }
        __syncthreads();
      }
    }  // layer loop
  }  // side loop

  // ---- F1: keys = rh @ wk, queries = rt @ wq ----
  {
    int i2 = t >> 6, k = t & 63;
    float ak = 0.f, aq = 0.f;
    for (int d = 0; d < DIM; ++d) {
      ak += sm.repr[0][i2][d] * wkm[(size_t)d*DK + k];
      aq += sm.repr[1][i2][d] * wqm[(size_t)d*DK + k];
    }
    sm.uu.f.keysl[i2][k] = ak;
    sm.uu.f.querl[i2][k] = aq;
  }
  // ---- F2b: repr norms ----
  {
    int sd = t >> 7, i = (t >> 5) & 3, j2 = t & 31;
    float s = 0.f;
    #pragma unroll
    for (int u2 = 0; u2 < 4; ++u2) {
      float v = sm.repr[sd][i][j2*4+u2];
      s += v*v;
    }
    for (int w = 1; w < 32; w <<= 1) s += __shfl_xor(s, w);
    if (j2 == 0) sm.scl[sd][i] = 1.f / fmaxf(sqrtf(s), 1e-12f);
  }
  __syncthreads();

  // ---- F2: att[i][j] ----
  {
    int pair = t >> 4, kk = t & 15;
    int i = pair >> 2, j = pair & 3;
    float a = 0.f;
    #pragma unroll
    for (int u2 = 0; u2 < 4; ++u2) {
      int k = kk*4+u2;
      a += tanhf(sm.uu.f.keysl[i][k] + sm.uu.f.querl[j][k] + cob[k]) * coa[k];
    }
    for (int w = 1; w < 16; w <<= 1) a += __shfl_xor(a, w);
    if (kk == 0) sm.uu.f.attw[pair] = a;
  }
  // ---- F3: u4[i][:] = repr_h[i] @ r_raw ----
  int rel = rels[g];
  if (t < DIM) {
    const float* rr = rel_emb + (size_t)rel * (DIM*DIM);
    float a0=0.f, a1=0.f, a2=0.f, a3=0.f;
    for (int d = 0; d < DIM; ++d) {
      float rv = rr[(size_t)d*DIM + t];
      a0 += sm.repr[0][0][d] * rv;
      a1 += sm.repr[0][1][d] * rv;
      a2 += sm.repr[0][2][d] * rv;
      a3 += sm.repr[0][3][d] * rv;
    }
    sm.uu.f.u4[0][t]=a0; sm.uu.f.u4[1][t]=a1; sm.uu.f.u4[2][t]=a2; sm.uu.f.u4[3][t]=a3;
  }
  __syncthreads();

  // ---- F4: scores + weighted sum ----
  {
    float rninv = 1.f / fmaxf(rnorm[rel], 1e-12f);
    int pair = t >> 4, kk = t & 15;
    int i = pair >> 2, j = pair & 3;
    float a = 0.f;
    #pragma unroll
    for (int u2 = 0; u2 < 8; ++u2) {
      int e = kk*8+u2;
      a += sm.uu.f.u4[i][e] * sm.repr[1][j][e];
    }
    for (int w = 1; w < 16; w <<= 1) a += __shfl_xor(a, w);
    if (kk == 0)
      sm.uu.f.red[pair] = sm.uu.f.attw[pair] * a * sm.scl[0][i] * sm.scl[1][j] * rninv;
  }
  __syncthreads();
  if (t == 0) {
    float s = 0.f;
    for (int p = 0; p < NB*NB; ++p) s += sm.uu.f.red[p];
    out[g] = s;
  }
}

extern "C" void kernel_launch(void* const* d_in, const int* in_sizes, int n_in,
                              void* d_out, int out_size, void* d_ws, size_t ws_size,
                              hipStream_t stream) {
  const float* xh      = (const float*)d_in[0];
  const float* xt      = (const float*)d_in[1];
  const int*   eh      = (const int*)d_in[2];
  const int*   et      = (const int*)d_in[3];
  // d_in[4] = batch (structurally n>>5; unused)
  const int*   rels    = (const int*)d_in[5];
  const float* W0      = (const float*)d_in[6];
  const float* Wr      = (const float*)d_in[7];
  const float* att_src = (const float*)d_in[8];
  const float* att_dst = (const float*)d_in[9];
  const float* gat_b   = (const float*)d_in[10];
  const float* srw     = (const float*)d_in[11];
  const float* srb     = (const float*)d_in[12];
  const float* sroot   = (const float*)d_in[13];
  const float* nw      = (const float*)d_in[14];
  const float* nb2_    = (const float*)d_in[15];
  const float* inw     = (const float*)d_in[16];
  const float* inb     = (const float*)d_in[17];
  const float* wqm     = (const float*)d_in[18];
  const float* wkm     = (const float*)d_in[19];
  const float* cob     = (const float*)d_in[20];
  const float* coa     = (const float*)d_in[21];
  const float* rel_emb = (const float*)d_in[22];
  float* out   = (float*)d_out;
  float* rnorm = (float*)d_ws;   // 86 floats

  // ws layout: [0,344) rnorm; [512, 512+256K) main W planes; then 32K wx planes
  const size_t NEED_W    = 512 + (size_t)2*65536*sizeof(unsigned short);
  const size_t NEED_FULL = NEED_W + (size_t)2*8192*sizeof(unsigned short);

  relnorm_kernel<<<NREL, 256, 0, stream>>>(rel_emb, rnorm);

  if (ws_size >= NEED_FULL) {
    unsigned short* wsp = (unsigned short*)((char*)d_ws + 512);
    unsigned short* wx  = wsp + 2*65536;
    wprep_kernel<<<256, 256, 0, stream>>>(W0, Wr, wsp);
    wxprep_kernel<<<64, 128, 0, stream>>>(W0, Wr, att_src, att_dst, srw, sroot, wx);
    ssi_kernel<true><<<NG, 256, 0, stream>>>(xh, xt, eh, et, rels, W0, Wr, wsp, wx,
        att_src, att_dst, gat_b, srw, srb, sroot, nw, nb2_, inw, inb,
        wqm, wkm, cob, coa, rel_emb, rnorm, out);
  } else if (ws_size >= NEED_W) {
    unsigned short* wsp = (unsigned short*)((char*)d_ws + 512);
    wprep_kernel<<<256, 256, 0, stream>>>(W0, Wr, wsp);
    ssi_kernel<false><<<NG, 256, 0, stream>>>(xh, xt, eh, et, rels, W0, Wr, wsp, nullptr,
        att_src, att_dst, gat_b, srw, srb, sroot, nw, nb2_, inw, inb,
        wqm, wkm, cob, coa, rel_emb, rnorm, out);
  } else {
    ssi_kernel<false><<<NG, 256, 0, stream>>>(xh, xt, eh, et, rels, W0, Wr, nullptr, nullptr,
        att_src, att_dst, gat_b, srw, srb, sroot, nw, nb2_, inw, inb,
        wqm, wkm, cob, coa, rel_emb, rnorm, out);
  }
}

// Round 11
// 1211.783 us; speedup vs baseline: 3.3248x; 1.0154x over previous
//
#include <hip/hip_runtime.h>
#include <math.h>

#define NG 8192          // graphs
#define NPG 32           // nodes per graph
#define NN (NG*NPG)      // 262144 nodes
#define NE (NN*4)        // 1048576 edges per side
#define EPG 128          // edges per graph
#define NEL (EPG+NPG)    // edges + self loops
#define FIN 70
#define DIM 128
#define XS 132           // x row stride in floats
#define TS 36            // h2t / Pt row stride (u16 / f32 units)
#define NB 4
#define DK 64
#define NREL 86

typedef __attribute__((ext_vector_type(8))) short short8;
typedef __attribute__((ext_vector_type(4))) float f32x4;
typedef __attribute__((ext_vector_type(4))) unsigned int u32x4;

__device__ inline unsigned cvtpk(float a, float b) {
  unsigned r;
  asm("v_cvt_pk_bf16_f32 %0, %1, %2" : "=v"(r) : "v"(a), "v"(b));
  return r;   // lo16 = bf16(a), hi16 = bf16(b), RNE
}
__device__ inline float lo16f(unsigned u) { return __uint_as_float(u << 16); }
__device__ inline float hi16f(unsigned u) { return __uint_as_float(u & 0xffff0000u); }
__device__ inline float bf16f(unsigned short h) {
  return __uint_as_float(((unsigned int)h) << 16);
}

// 8 f32 -> hi/lo bf16x8 fragments (2-term split, v = hi + lo + O(2^-17 |v|))
__device__ inline void split8(const f32x4& a, const f32x4& b, short8& hi, short8& lo) {
  u32x4 H, L;
  #pragma unroll
  for (int p = 0; p < 2; ++p) {
    float x0 = a[2*p], x1 = a[2*p+1];
    unsigned h = cvtpk(x0, x1);
    H[p] = h;
    L[p] = cvtpk(x0 - lo16f(h), x1 - hi16f(h));
  }
  #pragma unroll
  for (int p = 0; p < 2; ++p) {
    float x0 = b[2*p], x1 = b[2*p+1];
    unsigned h = cvtpk(x0, x1);
    H[2+p] = h;
    L[2+p] = cvtpk(x0 - lo16f(h), x1 - hi16f(h));
  }
  hi = __builtin_bit_cast(short8, H);
  lo = __builtin_bit_cast(short8, L);
}

// 8 contiguous bf16, 8B-aligned (LDS rows) -> short8 via 2x b64
__device__ inline short8 ld8(const unsigned short* p) {
  union { short8 s; uint2 u[2]; } U;
  U.u[0] = *(const uint2*)p;
  U.u[1] = *(const uint2*)(p + 4);
  return U.s;
}
// 8 contiguous bf16, 16B-aligned (global W planes) -> short8 via b128
__device__ inline short8 ld16B(const unsigned short* p) {
  u32x4 u = *(const u32x4*)p;
  return __builtin_bit_cast(short8, u);
}

struct Smem {
  float x[NPG][XS];               // 16.9KB node features (f32)
  unsigned short h2thi[DIM][TS];  // 9.2KB h2 transposed, bf16 hi: h2thi[c][node]
  unsigned short h2tlo[DIM][TS];  // 9.2KB residual
  union {
    float Pt[2][NPG][TS];         // 9.2KB P'[hd][dst][src]; after C4cd reused as bf16 hi|lo
    struct {                      // final phases
      float keysl[NB][DK];
      float querl[NB][DK];
      float attw[NB*NB];
      float red[NB*NB];
      float u4[4][DIM];           // RESCAL u = repr_h @ r
    } f;
  } uu;
  int   srcl[EPG];
  int   dstl[EPG];
  float asrc[NPG][2];
  float adst[NPG][2];
  float wred[4][2];
  float pl[NPG];
  float ql[NPG];
  float hrq[4][NPG];              // FAST: hr0,hr1,hq0,hq1 per node
  float pqp[2][NPG];              // FAST: p partial per (head,node)
  float pqq[2][NPG];              // FAST: q partial per (head,node)
  float cbl[NB];                  // FAST: gat_b . srw per layer
  float sval[NPG];
  float sacc[NPG];
  float repr[2][NB][DIM];
  float scl[2][NB];
};

__global__ __launch_bounds__(256) void relnorm_kernel(
    const float* __restrict__ re, float* __restrict__ outn) {
  int r = blockIdx.x;
  const float* row = re + (size_t)r * (DIM*DIM);
  float s = 0.f;
  for (int i = threadIdx.x; i < DIM*DIM; i += 256) { float v = row[i]; s += v*v; }
  for (int w = 1; w < 64; w <<= 1) s += __shfl_xor(s, w);
  __shared__ float sred[4];
  if ((threadIdx.x & 63) == 0) sred[threadIdx.x >> 6] = s;
  __syncthreads();
  if (threadIdx.x == 0) outn[r] = sqrtf(sred[0]+sred[1]+sred[2]+sred[3]);
}

// W -> transposed bf16 hi/lo planes in ws: hi[l][c][k], lo[l][c][k]
__global__ __launch_bounds__(256) void wprep_kernel(
    const float* __restrict__ W0, const float* __restrict__ Wr,
    unsigned short* __restrict__ wsp) {
  int idx = blockIdx.x * 256 + threadIdx.x;   // 4*128*128
  int l = idx >> 14;
  int k = (idx >> 7) & 127;
  int c = idx & 127;
  float v;
  if (l == 0) v = (k < FIN) ? W0[(size_t)k*DIM + c] : 0.f;
  else        v = Wr[(size_t)(l-1)*DIM*DIM + (size_t)k*DIM + c];
  unsigned h = cvtpk(v, 0.f);
  unsigned lo = cvtpk(v - lo16f(h), 0.f);
  int o = (l << 14) + c*128 + k;
  wsp[o] = (unsigned short)h;
  wsp[65536 + o] = (unsigned short)lo;
}

// Projected extra columns: wx[li][j][k] = sum_c W[k][c]*v_j[c], j in 0..7:
// 0:as_h0 1:ad_h0 2:as_h1 3:ad_h1 4:rw_h0 5:rw_h1 6:ro_h0 7:ro_h1; j>=8 zero.
__global__ __launch_bounds__(128) void wxprep_kernel(
    const float* __restrict__ W0, const float* __restrict__ Wr,
    const float* __restrict__ att_src, const float* __restrict__ att_dst,
    const float* __restrict__ srw, const float* __restrict__ sroot,
    unsigned short* __restrict__ wx) {
  int b = blockIdx.x;          // 64 = 4 li * 16 j
  int li = b >> 4, j = b & 15;
  int k = threadIdx.x;         // 0..127
  const int K = (li == 0) ? FIN : DIM;
  float val = 0.f;
  if (j < 8 && k < K) {
    const float* Wrow = (li == 0) ? (W0 + (size_t)k*DIM)
                                  : (Wr + (size_t)(li-1)*DIM*DIM + (size_t)k*DIM);
    const float* v; int c0;
    switch (j) {
      case 0: v = att_src + ((size_t)li*2+0)*64; c0 = 0;  break;
      case 1: v = att_dst + ((size_t)li*2+0)*64; c0 = 0;  break;
      case 2: v = att_src + ((size_t)li*2+1)*64; c0 = 64; break;
      case 3: v = att_dst + ((size_t)li*2+1)*64; c0 = 64; break;
      case 4: v = srw   + (size_t)li*DIM;        c0 = 0;  break;
      case 5: v = srw   + (size_t)li*DIM;        c0 = 64; break;
      case 6: v = sroot + (size_t)li*DIM;        c0 = 0;  break;
      default: v = sroot + (size_t)li*DIM;       c0 = 64; break;
    }
    for (int c = 0; c < 64; ++c) {
      float vc = (j < 4) ? v[c] : v[c0 + c];
      val += Wrow[c0 + c] * vc;
    }
  }
  unsigned h = cvtpk(val, 0.f);
  unsigned lo = cvtpk(val - lo16f(h), 0.f);
  int o = (li << 11) + j*128 + k;
  wx[o] = (unsigned short)h;
  wx[8192 + o] = (unsigned short)lo;
}

template <bool FAST>
__global__ __launch_bounds__(256, 3) void ssi_kernel(
    const float* __restrict__ xh, const float* __restrict__ xt,
    const int* __restrict__ eh, const int* __restrict__ et,
    const int* __restrict__ rels,
    const float* __restrict__ W0, const float* __restrict__ Wr,
    const unsigned short* __restrict__ wsp,   // nullptr -> in-register W split
    const unsigned short* __restrict__ wx,    // FAST only
    const float* __restrict__ att_src, const float* __restrict__ att_dst,
    const float* __restrict__ gat_b,
    const float* __restrict__ srw, const float* __restrict__ srb,
    const float* __restrict__ sroot,
    const float* __restrict__ nw, const float* __restrict__ nb2,
    const float* __restrict__ inw, const float* __restrict__ inb,
    const float* __restrict__ wqm, const float* __restrict__ wkm,
    const float* __restrict__ cob, const float* __restrict__ coa,
    const float* __restrict__ rel_emb, const float* __restrict__ rnorm,
    float* __restrict__ out)
{
  __shared__ Smem sm;
  const int t = threadIdx.x;
  const int g = blockIdx.x;
  const int n0 = g * NPG;
  const int lw = t & 63;
  const int r0 = lw & 15;        // MFMA row/col lane within 16-tile
  const int g4 = lw >> 4;        // MFMA k-group
  const int nb = (t >> 6) * 32;  // wave's 32-col band
  const int hdw = t >> 7;        // wave's head for C5

  for (int side = 0; side < 2; ++side) {
    const float* xin = side ? xt : xh;
    const int*   ed  = side ? et : eh;

    // ---- load edges (local ids); FAST: fold cb[li] = gat_b.srw (side 0) ----
    if (t < EPG) {
      sm.srcl[t] = ed[g*EPG + t] - n0;
      sm.dstl[t] = ed[NE + g*EPG + t] - n0;
    }
    if (FAST && side == 0 && t >= 128) {
      int li2 = (t-128) >> 5, ln = (t-128) & 31;
      float s_ = 0.f;
      #pragma unroll
      for (int m = 0; m < 4; ++m) {
        int c = ln + 32*m;
        s_ += gat_b[(size_t)li2*DIM + c] * srw[(size_t)li2*DIM + c];
      }
      for (int w = 1; w < 32; w <<= 1) s_ += __shfl_xor(s_, w);
      if (ln == 0) sm.cbl[li2] = s_;
    }
    // ---- input layernorm over FIN=70, zero-pad [70,96) ----
    {
      int n = t >> 3, j = t & 7;
      float s = 0.f, s2 = 0.f;
      for (int f = j; f < FIN; f += 8) {
        float v = xin[(size_t)(n0+n)*FIN + f];
        s += v; s2 += v*v;
      }
      for (int w = 1; w < 8; w <<= 1) { s += __shfl_xor(s, w); s2 += __shfl_xor(s2, w); }
      float mu  = s * (1.f/FIN);
      float var = s2 * (1.f/FIN) - mu*mu;
      float inv = rsqrtf(var + 1e-5f);
      for (int f = j; f < FIN; f += 8) {
        float v = xin[(size_t)(n0+n)*FIN + f];
        sm.x[n][f] = (v - mu) * inv * inw[f] + inb[f];
      }
      for (int f = FIN + j; f < 96; f += 8) sm.x[n][f] = 0.f;
    }
    __syncthreads();

    for (int li = 0; li < NB; ++li) {
      // ---- C1: h2 = x @ W via MFMA; epilogue stores h2 transposed bf16 hi/lo.
      //      FAST: wave 0 also computes the projected extra tile. ----
      {
        const float* W = (li == 0) ? W0 : (Wr + (size_t)(li-1)*DIM*DIM);
        const int K  = (li == 0) ? FIN : DIM;
        const int KS = (li == 0) ? 3 : 4;
        f32x4 acc[2][2];
        f32x4 accx[2];
        #pragma unroll
        for (int mt = 0; mt < 2; ++mt) {
          accx[mt] = (f32x4){0.f,0.f,0.f,0.f};
          #pragma unroll
          for (int nt = 0; nt < 2; ++nt)
            acc[mt][nt] = (f32x4){0.f,0.f,0.f,0.f};
        }
        const unsigned short* Wxh = FAST ? (wx + (li << 11)) : nullptr;
        const unsigned short* Wxl = FAST ? (wx + 8192 + (li << 11)) : nullptr;
        for (int ks = 0; ks < KS; ++ks) {
          const int k0 = ks*32 + g4*8;
          short8 ah[2], al[2], bh[2], bl[2];
          #pragma unroll
          for (int mt = 0; mt < 2; ++mt) {
            f32x4 va = *(const f32x4*)&sm.x[mt*16 + r0][k0];
            f32x4 vb = *(const f32x4*)&sm.x[mt*16 + r0][k0+4];
            split8(va, vb, ah[mt], al[mt]);
          }
          if (wsp) {
            const unsigned short* Wh = wsp + (li << 14);
            const unsigned short* Wl = wsp + 65536 + (li << 14);
            #pragma unroll
            for (int nt = 0; nt < 2; ++nt) {
              const int c = nb + nt*16 + r0;
              bh[nt] = ld16B(Wh + c*128 + k0);
              bl[nt] = ld16B(Wl + c*128 + k0);
            }
          } else {
            #pragma unroll
            for (int nt = 0; nt < 2; ++nt) {
              const int c = nb + nt*16 + r0;
              f32x4 wa, wb;
              #pragma unroll
              for (int j = 0; j < 4; ++j) {
                int ka = k0 + j, kb = k0 + 4 + j;
                wa[j] = (ka < K) ? W[(size_t)ka*DIM + c] : 0.f;
                wb[j] = (kb < K) ? W[(size_t)kb*DIM + c] : 0.f;
              }
              split8(wa, wb, bh[nt], bl[nt]);
            }
          }
          #pragma unroll
          for (int mt = 0; mt < 2; ++mt)
            #pragma unroll
            for (int nt = 0; nt < 2; ++nt) {
              acc[mt][nt] = __builtin_amdgcn_mfma_f32_16x16x32_bf16(ah[mt], bh[nt], acc[mt][nt], 0,0,0);
              acc[mt][nt] = __builtin_amdgcn_mfma_f32_16x16x32_bf16(ah[mt], bl[nt], acc[mt][nt], 0,0,0);
              acc[mt][nt] = __builtin_amdgcn_mfma_f32_16x16x32_bf16(al[mt], bh[nt], acc[mt][nt], 0,0,0);
              acc[mt][nt] = __builtin_amdgcn_mfma_f32_16x16x32_bf16(al[mt], bl[nt], acc[mt][nt], 0,0,0);
            }
          if (FAST && t < 64) {   // wave 0: projected extra tile
            short8 bxh = ld16B(Wxh + r0*128 + k0);
            short8 bxl = ld16B(Wxl + r0*128 + k0);
            #pragma unroll
            for (int mt = 0; mt < 2; ++mt) {
              accx[mt] = __builtin_amdgcn_mfma_f32_16x16x32_bf16(ah[mt], bxh, accx[mt], 0,0,0);
              accx[mt] = __builtin_amdgcn_mfma_f32_16x16x32_bf16(ah[mt], bxl, accx[mt], 0,0,0);
              accx[mt] = __builtin_amdgcn_mfma_f32_16x16x32_bf16(al[mt], bxh, accx[mt], 0,0,0);
              accx[mt] = __builtin_amdgcn_mfma_f32_16x16x32_bf16(al[mt], bxl, accx[mt], 0,0,0);
            }
          }
        }
        // D: col = nb+nt*16+r0, row = mt*16+g4*4+q -> store transposed bf16 hi/lo
        #pragma unroll
        for (int mt = 0; mt < 2; ++mt)
          #pragma unroll
          for (int nt = 0; nt < 2; ++nt) {
            const int c = nb + nt*16 + r0;
            const int row0 = mt*16 + g4*4;
            f32x4 a = acc[mt][nt];
            unsigned h0 = cvtpk(a[0], a[1]), h1 = cvtpk(a[2], a[3]);
            unsigned l0 = cvtpk(a[0]-lo16f(h0), a[1]-hi16f(h0));
            unsigned l1 = cvtpk(a[2]-lo16f(h1), a[3]-hi16f(h1));
            *(uint2*)&sm.h2thi[c][row0] = make_uint2(h0, h1);
            *(uint2*)&sm.h2tlo[c][row0] = make_uint2(l0, l1);
          }
        if (FAST && t < 64 && r0 < 8) {
          #pragma unroll
          for (int mt = 0; mt < 2; ++mt)
            #pragma unroll
            for (int q = 0; q < 4; ++q) {
              int n = mt*16 + g4*4 + q;
              float v = accx[mt][q];
              switch (r0) {
                case 0: sm.asrc[n][0] = v; break;
                case 1: sm.adst[n][0] = v; break;
                case 2: sm.asrc[n][1] = v; break;
                case 3: sm.adst[n][1] = v; break;
                default: sm.hrq[r0-4][n] = v;
              }
            }
        }
      }
      __syncthreads();

      // ---- C2 (non-FAST only): a_src/a_dst from h2t; zero Pt ----
      if (!FAST) {
        int n = t >> 3, hd = (t >> 2) & 1, j = t & 3;
        const float* as = att_src + ((size_t)li*2 + hd)*64;
        const float* ad = att_dst + ((size_t)li*2 + hd)*64;
        float ss = 0.f, sd = 0.f;
        #pragma unroll
        for (int u2 = 0; u2 < 16; ++u2) {
          int cl = u2*4 + j;
          int c = hd*64 + cl;
          float hv = bf16f(sm.h2thi[c][n]) + bf16f(sm.h2tlo[c][n]);
          ss += hv * as[cl];
          sd += hv * ad[cl];
        }
        ss += __shfl_xor(ss,1); ss += __shfl_xor(ss,2);
        sd += __shfl_xor(sd,1); sd += __shfl_xor(sd,2);
        if (j == 0) { sm.asrc[n][hd] = ss; sm.adst[n][hd] = sd; }
        float* Pz = &sm.uu.Pt[0][0][0];
        for (int idx = t; idx < 2*NPG*TS; idx += 256) Pz[idx] = 0.f;
        __syncthreads();
      }

      // ---- C3+C4a fused: alpha in registers + block max; FAST also zeros Pt ----
      float al0 = -1e30f, al1 = -1e30f;
      int es = 0, edd = 0;
      if (t < NEL) {
        es  = (t < EPG) ? sm.srcl[t] : (t - EPG);
        edd = (t < EPG) ? sm.dstl[t] : (t - EPG);
        float a0 = sm.asrc[es][0] + sm.adst[edd][0];
        float a1 = sm.asrc[es][1] + sm.adst[edd][1];
        al0 = (a0 > 0.f) ? a0 : 0.2f*a0;
        al1 = (a1 > 0.f) ? a1 : 0.2f*a1;
      }
      if (FAST) {
        float* Pz = &sm.uu.Pt[0][0][0];
        for (int idx = t; idx < 2*NPG*TS; idx += 256) Pz[idx] = 0.f;
      }
      {
        float m0 = al0, m1 = al1;
        for (int w = 1; w < 64; w <<= 1) {
          m0 = fmaxf(m0, __shfl_xor(m0, w));
          m1 = fmaxf(m1, __shfl_xor(m1, w));
        }
        if ((t & 63) == 0) { sm.wred[t>>6][0] = m0; sm.wred[t>>6][1] = m1; }
      }
      __syncthreads();

      // ---- C4b: scatter exp into Pt[hd][dst][src]; zero sacc ----
      if (t < NEL) {
        float M0 = fmaxf(fmaxf(sm.wred[0][0], sm.wred[1][0]),
                         fmaxf(sm.wred[2][0], sm.wred[3][0]));
        float M1 = fmaxf(fmaxf(sm.wred[0][1], sm.wred[1][1]),
                         fmaxf(sm.wred[2][1], sm.wred[3][1]));
        atomicAdd(&sm.uu.Pt[0][edd][es], __expf(al0 - M0));
        atomicAdd(&sm.uu.Pt[1][edd][es], __expf(al1 - M1));
      } else if (t < NEL + NPG) {
        sm.sacc[t - NEL] = 0.f;
      }
      __syncthreads();

      // ---- C4cd: den in-register, scale, FAST p/q partials; part B converts to
      //      bf16 and (FAST) folds the C6b-1 sacc scatter ----
      {
        int hd = t >> 7, r = (t >> 2) & 31, s0 = (t & 3) * 8;
        f32x4 pa = *(const f32x4*)&sm.uu.Pt[hd][r][s0];
        f32x4 pb = *(const f32x4*)&sm.uu.Pt[hd][r][s0+4];
        float rs = pa[0]+pa[1]+pa[2]+pa[3]+pb[0]+pb[1]+pb[2]+pb[3];
        rs += __shfl_xor(rs, 1);
        rs += __shfl_xor(rs, 2);
        float dv = 1.f / (rs + 1e-16f);
        #pragma unroll
        for (int q = 0; q < 4; ++q) { pa[q] *= dv; pb[q] *= dv; }
        if (FAST) {   // p/q partials for this (head, dst-row)
          f32x4 h0 = *(const f32x4*)&sm.hrq[hd][s0];
          f32x4 h1 = *(const f32x4*)&sm.hrq[hd][s0+4];
          f32x4 q0 = *(const f32x4*)&sm.hrq[2+hd][s0];
          f32x4 q1 = *(const f32x4*)&sm.hrq[2+hd][s0+4];
          float pp = 0.f, qq = 0.f;
          #pragma unroll
          for (int i = 0; i < 4; ++i) {
            pp += pa[i]*h0[i] + pb[i]*h1[i];
            qq += pa[i]*q0[i] + pb[i]*q1[i];
          }
          pp += __shfl_xor(pp, 1); pp += __shfl_xor(pp, 2);
          qq += __shfl_xor(qq, 1); qq += __shfl_xor(qq, 2);
          if ((t & 3) == 0) { sm.pqp[hd][r] = pp; sm.pqq[hd][r] = qq; }
        }
        __syncthreads();   // f32 Pt reads + pqp writes done
        unsigned short* Pu = (unsigned short*)&sm.uu.Pt[0][0][0];
        const int LO = 2*NPG*TS;
        int base = (hd*NPG + r)*TS + s0;
        unsigned h0 = cvtpk(pa[0], pa[1]), h1 = cvtpk(pa[2], pa[3]);
        unsigned h2_ = cvtpk(pb[0], pb[1]), h3 = cvtpk(pb[2], pb[3]);
        unsigned l0 = cvtpk(pa[0]-lo16f(h0), pa[1]-hi16f(h0));
        unsigned l1 = cvtpk(pa[2]-lo16f(h1), pa[3]-hi16f(h1));
        unsigned l2 = cvtpk(pb[0]-lo16f(h2_), pb[1]-hi16f(h2_));
        unsigned l3 = cvtpk(pb[2]-lo16f(h3), pb[3]-hi16f(h3));
        *(uint2*)(Pu + base)     = make_uint2(h0, h1);
        *(uint2*)(Pu + base + 4) = make_uint2(h2_, h3);
        *(uint2*)(Pu + LO + base)     = make_uint2(l0, l1);
        *(uint2*)(Pu + LO + base + 4) = make_uint2(l2, l3);
        if (FAST && t < EPG) {   // folded C6b-1 scatter
          int s = sm.srcl[t], d = sm.dstl[t];
          atomicAdd(&sm.sacc[d], sm.pqp[0][s] + sm.pqp[1][s] + sm.cbl[li]);
        }
      }
      __syncthreads();

      // ---- C5: x = P' @ h2 via MFMA (3 cross terms) ----
      f32x4 acc5[2][2];
      {
        const unsigned short* Pu = (const unsigned short*)&sm.uu.Pt[0][0][0];
        const int LO = 2*NPG*TS;
        const int k0 = g4*8;
        #pragma unroll
        for (int mt = 0; mt < 2; ++mt)
          #pragma unroll
          for (int nt = 0; nt < 2; ++nt)
            acc5[mt][nt] = (f32x4){0.f,0.f,0.f,0.f};
        short8 Ah[2], Al[2], Bh[2], Bl[2];
        #pragma unroll
        for (int mt = 0; mt < 2; ++mt) {
          int base = (hdw*NPG + mt*16 + r0)*TS + k0;
          Ah[mt] = ld8(Pu + base);
          Al[mt] = ld8(Pu + LO + base);
        }
        #pragma unroll
        for (int nt = 0; nt < 2; ++nt) {
          const int c = nb + nt*16 + r0;
          Bh[nt] = ld8(&sm.h2thi[c][k0]);
          Bl[nt] = ld8(&sm.h2tlo[c][k0]);
        }
        #pragma unroll
        for (int mt = 0; mt < 2; ++mt)
          #pragma unroll
          for (int nt = 0; nt < 2; ++nt) {
            acc5[mt][nt] = __builtin_amdgcn_mfma_f32_16x16x32_bf16(Ah[mt], Bh[nt], acc5[mt][nt], 0,0,0);
            acc5[mt][nt] = __builtin_amdgcn_mfma_f32_16x16x32_bf16(Ah[mt], Bl[nt], acc5[mt][nt], 0,0,0);
            acc5[mt][nt] = __builtin_amdgcn_mfma_f32_16x16x32_bf16(Al[mt], Bh[nt], acc5[mt][nt], 0,0,0);
          }
        if (!FAST) {   // non-FAST: store x now (C6a reads it next)
          #pragma unroll
          for (int nt = 0; nt < 2; ++nt) {
            const int c = nb + nt*16 + r0;
            float bc = gat_b[(size_t)li*DIM + c];
            #pragma unroll
            for (int mt = 0; mt < 2; ++mt)
              #pragma unroll
              for (int q = 0; q < 4; ++q)
                sm.x[mt*16 + g4*4 + q][c] = acc5[mt][nt][q] + bc;
          }
        }
        // FAST: C6b-2 softmax runs concurrently in wave 0 (sacc ready)
        if (FAST && t < NPG) {
          float s = sm.sacc[t] + srb[li] + sm.pqq[0][t] + sm.pqq[1][t];
          float m = s;
          for (int w = 1; w < 32; w <<= 1) m = fmaxf(m, __shfl_xor(m, w));
          float ex = __expf(s - m);
          float dn = ex;
          for (int w = 1; w < 32; w <<= 1) dn += __shfl_xor(dn, w);
          sm.sval[t] = ex / (dn + 1e-16f);
        }
      }
      __syncthreads();

      if (FAST) {
        // ---- EP (FAST): x write + in-register repr from live acc5 ----
        float sv[2][4];
        #pragma unroll
        for (int mt = 0; mt < 2; ++mt)
          #pragma unroll
          for (int q = 0; q < 4; ++q)
            sv[mt][q] = sm.sval[mt*16 + g4*4 + q];
        #pragma unroll
        for (int nt = 0; nt < 2; ++nt) {
          const int c = nb + nt*16 + r0;
          float bc = gat_b[(size_t)li*DIM + c];
          float pr = 0.f;
          #pragma unroll
          for (int mt = 0; mt < 2; ++mt)
            #pragma unroll
            for (int q = 0; q < 4; ++q) {
              float xv = acc5[mt][nt][q] + bc;
              sm.x[mt*16 + g4*4 + q][c] = xv;
              pr += xv * sv[mt][q];
            }
          pr += __shfl_xor(pr, 16);
          pr += __shfl_xor(pr, 32);
          if (g4 == 0) sm.repr[side][li][c] = pr;
        }
        __syncthreads();
      } else {
        // ---- C6a (non-FAST): p/q dots; zero sacc ----
        {
          int n = t >> 3, j = t & 7;
          const float* rw = srw   + (size_t)li*DIM;
          const float* ro = sroot + (size_t)li*DIM;
          float p = 0.f, q = 0.f;
          #pragma unroll
          for (int u2 = 0; u2 < 16; ++u2) {
            int c = u2*8 + j;
            float xv = sm.x[n][c];
            p += xv * rw[c];
            q += xv * ro[c];
          }
          for (int w = 1; w < 8; w <<= 1) { p += __shfl_xor(p,w); q += __shfl_xor(q,w); }
          if (j == 0) { sm.pl[n] = p; sm.ql[n] = q; }
        }
        __syncthreads();
        if (t < EPG) atomicAdd(&sm.sacc[sm.dstl[t]], sm.pl[sm.srcl[t]]);
        __syncthreads();
        if (t < NPG) {
          float s = sm.sacc[t] + srb[li] + sm.ql[t];
          float m = s;
          for (int w = 1; w < 32; w <<= 1) m = fmaxf(m, __shfl_xor(m, w));
          float ex = __expf(s - m);
          float dn = ex;
          for (int w = 1; w < 32; w <<= 1) dn += __shfl_xor(dn, w);
          sm.sval[t] = ex / (dn + 1e-16f);
        }
        __syncthreads();
        if (t < DIM) {
          float a = 0.f;
          #pragma unroll 8
          for (int n = 0; n < NPG; ++n) a += sm.x[n][t] * sm.sval[n];
          sm.repr[side][li][t] = a;
        }
        __syncthreads();
      }

      // ---- C7: x = elu(layernorm(x)) (skipped for last layer) ----
      if (li < NB-1) {
        int n = t >> 3, j = t & 7;
        float s = 0.f, s2 = 0.f;
        #pragma unroll
        for (int u2 = 0; u2 < 16; ++u2) {
          float v = sm.x[n][u2*8 + j];
          s += v; s2 += v*v;
        }
        for (int w = 1; w < 8; w <<= 1) { s += __shfl_xor(s,w); s2 += __shfl_xor(s2,w); }
        float mu  = s * (1.f/DIM);
        float var = s2 * (1.f/DIM) - mu*mu;
        float inv = rsqrtf(var + 1e-5f);
        const float* wv = nw  + (size_t)li*DIM;
        const float* bv = nb2 + (size_t)li*DIM;
        #pragma unroll
        for (int u2 = 0; u2 < 16; ++u2) {
          int c = u2*8 + j;
          float v = (sm.x[n][c] - mu) * inv * wv[c] + bv[c];
          sm.x[n][c] = (v > 0.f) ? v : (__expf(v) - 1.f);
        }
        __syncthreads();
      }
    }  // layer loop
  }  // side loop

  // ---- F1: keys = rh @ wk, queries = rt @ wq ----
  {
    int i2 = t >> 6, k = t & 63;
    float ak = 0.f, aq = 0.f;
    for (int d = 0; d < DIM; ++d) {
      ak += sm.repr[0][i2][d] * wkm[(size_t)d*DK + k];
      aq += sm.repr[1][i2][d] * wqm[(size_t)d*DK + k];
    }
    sm.uu.f.keysl[i2][k] = ak;
    sm.uu.f.querl[i2][k] = aq;
  }
  // ---- F2b: repr norms ----
  {
    int sd = t >> 7, i = (t >> 5) & 3, j2 = t & 31;
    float s = 0.f;
    #pragma unroll
    for (int u2 = 0; u2 < 4; ++u2) {
      float v = sm.repr[sd][i][j2*4+u2];
      s += v*v;
    }
    for (int w = 1; w < 32; w <<= 1) s += __shfl_xor(s, w);
    if (j2 == 0) sm.scl[sd][i] = 1.f / fmaxf(sqrtf(s), 1e-12f);
  }
  __syncthreads();

  // ---- F2: att[i][j] ----
  {
    int pair = t >> 4, kk = t & 15;
    int i = pair >> 2, j = pair & 3;
    float a = 0.f;
    #pragma unroll
    for (int u2 = 0; u2 < 4; ++u2) {
      int k = kk*4+u2;
      a += tanhf(sm.uu.f.keysl[i][k] + sm.uu.f.querl[j][k] + cob[k]) * coa[k];
    }
    for (int w = 1; w < 16; w <<= 1) a += __shfl_xor(a, w);
    if (kk == 0) sm.uu.f.attw[pair] = a;
  }
  // ---- F3: u4[i][:] = repr_h[i] @ r_raw ----
  int rel = rels[g];
  if (t < DIM) {
    const float* rr = rel_emb + (size_t)rel * (DIM*DIM);
    float a0=0.f, a1=0.f, a2=0.f, a3=0.f;
    for (int d = 0; d < DIM; ++d) {
      float rv = rr[(size_t)d*DIM + t];
      a0 += sm.repr[0][0][d] * rv;
      a1 += sm.repr[0][1][d] * rv;
      a2 += sm.repr[0][2][d] * rv;
      a3 += sm.repr[0][3][d] * rv;
    }
    sm.uu.f.u4[0][t]=a0; sm.uu.f.u4[1][t]=a1; sm.uu.f.u4[2][t]=a2; sm.uu.f.u4[3][t]=a3;
  }
  __syncthreads();

  // ---- F4: scores + weighted sum ----
  {
    float rninv = 1.f / fmaxf(rnorm[rel], 1e-12f);
    int pair = t >> 4, kk = t & 15;
    int i = pair >> 2, j = pair & 3;
    float a = 0.f;
    #pragma unroll
    for (int u2 = 0; u2 < 8; ++u2) {
      int e = kk*8+u2;
      a += sm.uu.f.u4[i][e] * sm.repr[1][j][e];
    }
    for (int w = 1; w < 16; w <<= 1) a += __shfl_xor(a, w);
    if (kk == 0)
      sm.uu.f.red[pair] = sm.uu.f.attw[pair] * a * sm.scl[0][i] * sm.scl[1][j] * rninv;
  }
  __syncthreads();
  if (t == 0) {
    float s = 0.f;
    for (int p = 0; p < NB*NB; ++p) s += sm.uu.f.red[p];
    out[g] = s;
  }
}

extern "C" void kernel_launch(void* const* d_in, const int* in_sizes, int n_in,
                              void* d_out, int out_size, void* d_ws, size_t ws_size,
                              hipStream_t stream) {
  const float* xh      = (const float*)d_in[0];
  const float* xt      = (const float*)d_in[1];
  const int*   eh      = (const int*)d_in[2];
  const int*   et      = (const int*)d_in[3];
  // d_in[4] = batch (structurally n>>5; unused)
  const int*   rels    = (const int*)d_in[5];
  const float* W0      = (const float*)d_in[6];
  const float* Wr      = (const float*)d_in[7];
  const float* att_src = (const float*)d_in[8];
  const float* att_dst = (const float*)d_in[9];
  const float* gat_b   = (const float*)d_in[10];
  const float* srw     = (const float*)d_in[11];
  const float* srb     = (const float*)d_in[12];
  const float* sroot   = (const float*)d_in[13];
  const float* nw      = (const float*)d_in[14];
  const float* nb2_    = (const float*)d_in[15];
  const float* inw     = (const float*)d_in[16];
  const float* inb     = (const float*)d_in[17];
  const float* wqm     = (const float*)d_in[18];
  const float* wkm     = (const float*)d_in[19];
  const float* cob     = (const float*)d_in[20];
  const float* coa     = (const float*)d_in[21];
  const float* rel_emb = (const float*)d_in[22];
  float* out   = (float*)d_out;
  float* rnorm = (float*)d_ws;   // 86 floats

  // ws layout: [0,344) rnorm; [512, 512+256K) main W planes; then 32K wx planes
  const size_t NEED_W    = 512 + (size_t)2*65536*sizeof(unsigned short);
  const size_t NEED_FULL = NEED_W + (size_t)2*8192*sizeof(unsigned short);

  relnorm_kernel<<<NREL, 256, 0, stream>>>(rel_emb, rnorm);

  if (ws_size >= NEED_FULL) {
    unsigned short* wsp = (unsigned short*)((char*)d_ws + 512);
    unsigned short* wx  = wsp + 2*65536;
    wprep_kernel<<<256, 256, 0, stream>>>(W0, Wr, wsp);
    wxprep_kernel<<<64, 128, 0, stream>>>(W0, Wr, att_src, att_dst, srw, sroot, wx);
    ssi_kernel<true><<<NG, 256, 0, stream>>>(xh, xt, eh, et, rels, W0, Wr, wsp, wx,
        att_src, att_dst, gat_b, srw, srb, sroot, nw, nb2_, inw, inb,
        wqm, wkm, cob, coa, rel_emb, rnorm, out);
  } else if (ws_size >= NEED_W) {
    unsigned short* wsp = (unsigned short*)((char*)d_ws + 512);
    wprep_kernel<<<256, 256, 0, stream>>>(W0, Wr, wsp);
    ssi_kernel<false><<<NG, 256, 0, stream>>>(xh, xt, eh, et, rels, W0, Wr, wsp, nullptr,
        att_src, att_dst, gat_b, srw, srb, sroot, nw, nb2_, inw, inb,
        wqm, wkm, cob, coa, rel_emb, rnorm, out);
  } else {
    ssi_kernel<false><<<NG, 256, 0, stream>>>(xh, xt, eh, et, rels, W0, Wr, nullptr, nullptr,
        att_src, att_dst, gat_b, srw, srb, sroot, nw, nb2_, inw, inb,
        wqm, wkm, cob, coa, rel_emb, rnorm, out);
  }
}